// Round 2
// baseline (395.550 us; speedup 1.0000x reference)
//
#include <hip/hip_runtime.h>
#include <math.h>

#define B 4
#define C 64
#define NN 65536

typedef __attribute__((ext_vector_type(8))) short short8;
typedef __attribute__((ext_vector_type(4))) short short4b;
typedef __attribute__((ext_vector_type(4))) float f32x4;

__device__ inline float bf2f(short s) {
  union { unsigned u; float f; } v; v.u = ((unsigned)(unsigned short)s) << 16; return v.f;
}
__device__ inline short f2bf(float f) {
  union { float f; unsigned u; } v; v.f = f;
  unsigned r = v.u + 0x7FFFu + ((v.u >> 16) & 1u);  // RNE
  return (short)(r >> 16);
}

// ---------------------------------------------------------------------------
// P1: pack w_qkv (first 128 rows) and w_m1 into MFMA A-frag order; zero gram2.
// A-frag (16x16x32): lane l holds A[m=l&15][k=(l>>4)*8+j], j=0..7.
__global__ void k_prep1(const float* __restrict__ wqkv, const float* __restrict__ wm1,
    short* __restrict__ apk, short* __restrict__ apm, float* __restrict__ gram2) {
  for (int idx = blockIdx.x * 256 + threadIdx.x; idx < 20480; idx += 16384) {
    if (idx < 8192) {
      const int j = idx & 7, lane = (idx >> 3) & 63, mt = (idx >> 9) & 7, cc = idx >> 12;
      const int o = mt * 16 + (lane & 15), c = cc * 32 + (lane >> 4) * 8 + j;
      apk[idx] = f2bf(wqkv[o * 64 + c]);
    } else if (idx < 12288) {
      const int k = idx - 8192;
      const int j = k & 7, lane = (k >> 3) & 63, mt = (k >> 9) & 3, cc = k >> 11;
      const int o = mt * 16 + (lane & 15), c = cc * 32 + (lane >> 4) * 8 + j;
      apm[k] = f2bf(wm1[o * 64 + c]);
    } else {
      gram2[idx - 12288] = 0.f;
    }
  }
}

// P2: pack w2 (OIHW 64x64x5x5) -> A-frag order [t][cc][mt][lane][j].
// Launched AFTER k_gram (its buffer aliases the dead qk region).
__global__ void k_prep2(const float* __restrict__ w2, short* __restrict__ apw2) {
  for (int idx = blockIdx.x * 256 + threadIdx.x; idx < 25 * 2 * 4 * 64 * 8; idx += 16384) {
    const int j = idx & 7, lane = (idx >> 3) & 63, mt = (idx >> 9) & 3,
              cc = (idx >> 11) & 1, t = idx >> 12;
    const int o = mt * 16 + (lane & 15);
    const int c = cc * 32 + (lane >> 4) * 8 + j;
    apw2[idx] = f2bf(w2[((size_t)o * 64 + c) * 25 + t]);
  }
}

// ---------------------------------------------------------------------------
// XT: x[b,c,n] fp32 -> x_t[b,n,64] bf16 (channel-innermost) via LDS transpose.
__global__ __launch_bounds__(256) void k_xt(const float* __restrict__ x,
    short* __restrict__ x_t) {
  __shared__ short lds[256 * 72];
  const int b = blockIdx.x >> 8, n0 = (blockIdx.x & 255) << 8;
  const int t = threadIdx.x;
#pragma unroll 4
  for (int c = 0; c < 64; ++c)
    lds[t * 72 + c] = f2bf(x[((size_t)(b * 64 + c)) * NN + n0 + t]);
  __syncthreads();
  short* dst = x_t + ((size_t)(b * NN + n0)) * 64;
#pragma unroll
  for (int it = 0; it < 8; ++it) {
    const int idx = it * 256 + t;
    const int nl = idx >> 3, cb = idx & 7;
    *(short8*)(dst + (size_t)nl * 64 + cb * 8) = *(const short8*)(lds + nl * 72 + cb * 8);
  }
}

// ---------------------------------------------------------------------------
// K1: qk 1x1 conv as MFMA GEMM: qk[b,o<128,n] = wqkv.x + b. B-frag straight
// from x_t (one short8 global load per k-chunk; no LDS).
__global__ __launch_bounds__(256, 4) void k_qk1x1(const short* __restrict__ x_t,
    const short* __restrict__ apk, const float* __restrict__ bias,
    short* __restrict__ qk) {
  const int b = blockIdx.x >> 10, ntile = blockIdx.x & 1023;
  const int wave = threadIdx.x >> 6, lane = threadIdx.x & 63;
  const int quad = lane >> 4, l15 = lane & 15;
  const int n = ntile * 64 + wave * 16 + l15;
  f32x4 acc[8];
#pragma unroll
  for (int mt = 0; mt < 8; ++mt) acc[mt] = (f32x4){0.f, 0.f, 0.f, 0.f};
#pragma unroll
  for (int cc = 0; cc < 2; ++cc) {
    const short8 bf = *(const short8*)(x_t + ((size_t)(b * NN + n)) * 64 + cc * 32 + quad * 8);
#pragma unroll
    for (int mt = 0; mt < 8; ++mt) {
      const short8 af = *(const short8*)(apk + ((cc * 8 + mt) * 64 + lane) * 8);
      acc[mt] = __builtin_amdgcn_mfma_f32_16x16x32_bf16(af, bf, acc[mt], 0, 0, 0);
    }
  }
#pragma unroll
  for (int mt = 0; mt < 8; ++mt)
#pragma unroll
    for (int reg = 0; reg < 4; ++reg) {
      const int o = mt * 16 + quad * 4 + reg;
      qk[((size_t)(b * 128 + o)) * NN + n] = f2bf(acc[mt][reg] + bias[o]);
    }
}

// ---------------------------------------------------------------------------
// K2: FUSED depthwise-3x3 + Gram, latency-optimized.
// Each wave owns one full image row (wave-uniform y): per s-step a lane
// computes 8 dw outputs of its channel (ch = l15 -> 8 q-rows / 8 k-rows of
// head h) from ONE aligned short8 load + 2 predicated edge scalars per tap
// row, then mfma(frag, frag) accumulates S.S^T. 4-wave LDS reduction before
// the global atomics (524K atomics total instead of 2M).
__global__ __launch_bounds__(256, 4) void k_gram(const short* __restrict__ qk,
    const float* __restrict__ wdw, const float* __restrict__ bdw,
    float* __restrict__ gram2) {
  __shared__ float red[4][256];
  const int bh = blockIdx.x >> 6, chunk = blockIdx.x & 63;
  const int b = bh >> 3, h = bh & 7;
  const int wave = threadIdx.x >> 6, lane = threadIdx.x & 63;
  const int quad = lane >> 4, l15 = lane & 15;
  const int ch = (l15 < 8) ? (h * 8 + l15) : (64 + h * 8 + (l15 - 8));
  const short* plane = qk + ((size_t)(b * 128 + ch)) * NN;
  float wreg[9];
#pragma unroll
  for (int i = 0; i < 9; ++i) wreg[i] = wdw[ch * 9 + i];
  const float bias = bdw[ch];
  const int row = chunk * 4 + wave;          // wave-uniform output row 0..255
  const short* prow = plane + row * 256;
  f32x4 acc = {0.f, 0.f, 0.f, 0.f};
  for (int s = 0; s < 8; ++s) {
    const int px0 = s * 32 + quad * 8;       // 8-aligned -> 16B-aligned loads
    float a[8];
#pragma unroll
    for (int j = 0; j < 8; ++j) a[j] = bias;
#pragma unroll
    for (int dy = 0; dy < 3; ++dy) {
      if (dy == 0 && row == 0) continue;     // wave-uniform branches
      if (dy == 2 && row == 255) continue;
      const short* pr = prow + (dy - 1) * 256 + px0;
      const short8 mid = *(const short8*)pr;
      float m[10];
      m[0] = 0.f;
      if (px0 > 0) m[0] = bf2f(pr[-1]);      // predicated: no OOB speculation
      m[9] = 0.f;
      if (px0 < 248) m[9] = bf2f(pr[8]);
#pragma unroll
      for (int k = 0; k < 8; ++k) m[k + 1] = bf2f(mid[k]);
      const float w0 = wreg[dy * 3], w1 = wreg[dy * 3 + 1], w2 = wreg[dy * 3 + 2];
#pragma unroll
      for (int j = 0; j < 8; ++j)
        a[j] = fmaf(w2, m[j + 2], fmaf(w1, m[j + 1], fmaf(w0, m[j], a[j])));
    }
    short8 frag;
#pragma unroll
    for (int j = 0; j < 8; ++j) frag[j] = f2bf(a[j]);
    acc = __builtin_amdgcn_mfma_f32_16x16x32_bf16(frag, frag, acc, 0, 0, 0);
  }
#pragma unroll
  for (int reg = 0; reg < 4; ++reg)
    red[wave][(quad * 4 + reg) * 16 + l15] = acc[reg];
  __syncthreads();
  {
    const int e = threadIdx.x;
    const float s4 = red[0][e] + red[1][e] + red[2][e] + red[3][e];
    atomicAdd(&gram2[bh * 256 + e], s4);
  }
}

// ---------------------------------------------------------------------------
// K3: m1 1x1 conv + BN as MFMA GEMM -> y_t[b,n,64] bf16 via LDS repack.
__global__ __launch_bounds__(256, 4) void k_m1_bn(const short* __restrict__ x_t,
    const short* __restrict__ apm, const float* __restrict__ gamma,
    const float* __restrict__ beta, const float* __restrict__ mean,
    const float* __restrict__ var, short* __restrict__ y_t) {
  __shared__ short lds[64 * 72];
  const int b = blockIdx.x >> 10, ntile = blockIdx.x & 1023;
  const int wave = threadIdx.x >> 6, lane = threadIdx.x & 63;
  const int quad = lane >> 4, l15 = lane & 15;
  const int n = ntile * 64 + wave * 16 + l15;
  f32x4 acc[4];
#pragma unroll
  for (int mt = 0; mt < 4; ++mt) acc[mt] = (f32x4){0.f, 0.f, 0.f, 0.f};
#pragma unroll
  for (int cc = 0; cc < 2; ++cc) {
    const short8 bf = *(const short8*)(x_t + ((size_t)(b * NN + n)) * 64 + cc * 32 + quad * 8);
#pragma unroll
    for (int mt = 0; mt < 4; ++mt) {
      const short8 af = *(const short8*)(apm + ((cc * 4 + mt) * 64 + lane) * 8);
      acc[mt] = __builtin_amdgcn_mfma_f32_16x16x32_bf16(af, bf, acc[mt], 0, 0, 0);
    }
  }
#pragma unroll
  for (int mt = 0; mt < 4; ++mt)
#pragma unroll
    for (int reg = 0; reg < 4; ++reg) {
      const int o = mt * 16 + quad * 4 + reg;
      const float sc = gamma[o] * rsqrtf(var[o] + 1e-5f);
      lds[(wave * 16 + l15) * 72 + o] = f2bf((acc[mt][reg] - mean[o]) * sc + beta[o]);
    }
  __syncthreads();
  short* dst = y_t + ((size_t)(b * NN + ntile * 64)) * 64;
#pragma unroll
  for (int it = 0; it < 2; ++it) {
    const int idx = it * 256 + threadIdx.x;
    const int lcol = idx >> 3, cb = idx & 7;
    *(short8*)(dst + (size_t)lcol * 64 + cb * 8) = *(const short8*)(lds + lcol * 72 + cb * 8);
  }
}

// ---------------------------------------------------------------------------
// K4: conv5x5 implicit-GEMM MFMA, XOR-swizzled staging (conflict-free),
// 4 blocks/CU. Epilogue v = x*(1+sigmoid(.)) -> v_t[b,n,64] via LDS repack
// (stride 76 shorts, b64-packed writes).
// Staging layout: L = rr*68+col (rr<8, col<68), channel-quad cb (16B each);
// byte = (L*64 + cb*16) ^ (((L>>1)&3)<<4). The XOR key is a bijection over
// any 8 consecutive L per quad -> every 16B granule gets exactly 8/64 lanes
// on both ds_write and ds_read (conflict-free b128).
__global__ __launch_bounds__(256, 4) void k_conv5(const short* __restrict__ y_t,
    const short* __restrict__ apw2, const short* __restrict__ x_t,
    short* __restrict__ v_t) {
  __shared__ short slds[4 * 64 * 76];  // 38,912 B >= staging 34,816 B
  char* sb = (char*)slds;
  const int b = blockIdx.x >> 8;
  const int rg = (blockIdx.x >> 2) & 63, cg = blockIdx.x & 3;
  const int r0 = rg * 4, x0 = cg * 64;
  const int wave = threadIdx.x >> 6, lane = threadIdx.x & 63;
  const int quad = lane >> 4, l15 = lane & 15;
  f32x4 acc[4][4];
#pragma unroll
  for (int mt = 0; mt < 4; ++mt)
#pragma unroll
    for (int nt = 0; nt < 4; ++nt) acc[mt][nt] = (f32x4){0.f, 0.f, 0.f, 0.f};
  for (int cc = 0; cc < 2; ++cc) {
    if (cc) __syncthreads();
    for (int idx = threadIdx.x; idx < 8 * 68 * 4; idx += 256) {
      const int rr = idx / 272, rem = idx - rr * 272;
      const int col = rem >> 2, cb = rem & 3;
      const int gr = r0 - 2 + rr, gc = x0 - 2 + col;
      short8 val = {0, 0, 0, 0, 0, 0, 0, 0};
      if (gr >= 0 && gr < 256 && gc >= 0 && gc < 256)
        val = *(const short8*)(y_t + ((size_t)(b * NN + gr * 256 + gc)) * 64 + cc * 32 + cb * 8);
      const int L = rr * 68 + col;
      *(short8*)(sb + ((L * 64 + cb * 16) ^ (((L >> 1) & 3) << 4))) = val;
    }
    __syncthreads();
    for (int t = 0; t < 25; ++t) {
      const int dy = t / 5 - 2, dx = t % 5 - 2;
      short8 a[4];
#pragma unroll
      for (int mt = 0; mt < 4; ++mt)
        a[mt] = *(const short8*)(apw2 + (((t * 2 + cc) * 4 + mt) * 64 + lane) * 8);
      const int rr = wave + 2 + dy;
#pragma unroll
      for (int nt = 0; nt < 4; ++nt) {
        const int L = rr * 68 + nt * 16 + l15 + 2 + dx;
        const short8 bf =
            *(const short8*)(sb + ((L * 64 + quad * 16) ^ (((L >> 1) & 3) << 4)));
#pragma unroll
        for (int mt = 0; mt < 4; ++mt)
          acc[mt][nt] = __builtin_amdgcn_mfma_f32_16x16x32_bf16(a[mt], bf, acc[mt][nt], 0, 0, 0);
      }
    }
  }
  __syncthreads();  // done reading staging; reuse slds as [row4][col64] stride 76
  const int row = r0 + wave;
#pragma unroll
  for (int nt = 0; nt < 4; ++nt) {
    const int lcol = nt * 16 + l15;
    const short* xp = x_t + ((size_t)(b * NN + row * 256 + x0 + lcol)) * 64 + quad * 4;
#pragma unroll
    for (int mt = 0; mt < 4; ++mt) {
      const short4b xv4 = *(const short4b*)(xp + mt * 16);
      short4b pk;
#pragma unroll
      for (int reg = 0; reg < 4; ++reg) {
        const float sg = 1.f / (1.f + __expf(-acc[mt][nt][reg]));
        pk[reg] = f2bf(bf2f(xv4[reg]) * (1.f + sg));
      }
      *(short4b*)(slds + (wave * 64 + lcol) * 76 + mt * 16 + quad * 4) = pk;
    }
  }
  __syncthreads();
#pragma unroll
  for (int it = 0; it < 8; ++it) {
    const int idx = it * 256 + threadIdx.x;
    const int cb = idx & 7, lcol = (idx >> 3) & 63, rr = idx >> 9;
    *(short8*)(v_t + ((size_t)(b * NN + (r0 + rr) * 256 + x0 + lcol)) * 64 + cb * 8) =
        *(const short8*)(slds + (rr * 64 + lcol) * 76 + cb * 8);
  }
}

// ---------------------------------------------------------------------------
// K5: softmax from gram2, fold wproj, emit E directly in bf16 A-frag order:
// Epack[b][cc][mt][lane][j] with A[m=o][k=cv].
__global__ __launch_bounds__(256) void k_attn_e(const float* __restrict__ gram2,
    const float* __restrict__ temp, const float* __restrict__ wproj,
    short* __restrict__ Epack) {
  __shared__ float attn[2048];
  const int t = threadIdx.x;
  {
    const int b = t >> 6, h = (t >> 3) & 7, c = t & 7;
    const float* g = gram2 + (b * 8 + h) * 256;
    const float qn = fmaxf(sqrtf(g[c * 16 + c]), 1e-12f);
    const float tp = temp[h];
    float row[8];
    float mx = -1e30f;
#pragma unroll
    for (int d = 0; d < 8; ++d) {
      const float kn = fmaxf(sqrtf(g[(8 + d) * 16 + (8 + d)]), 1e-12f);
      row[d] = g[c * 16 + 8 + d] / (qn * kn) * tp;
      mx = fmaxf(mx, row[d]);
    }
    float s = 0.f;
#pragma unroll
    for (int d = 0; d < 8; ++d) { row[d] = __expf(row[d] - mx); s += row[d]; }
    const float inv = 1.f / s;
#pragma unroll
    for (int d = 0; d < 8; ++d) attn[t * 8 + d] = row[d] * inv;
  }
  __syncthreads();
  for (int idx = t; idx < 16384; idx += 256) {
    const int j = idx & 7, lane = (idx >> 3) & 63, mt = (idx >> 9) & 3,
              cc = (idx >> 11) & 1, b = idx >> 12;
    const int o = mt * 16 + (lane & 15);
    const int cv = cc * 32 + (lane >> 4) * 8 + j;
    const int h = cv >> 3, d = cv & 7;
    float a = 0.f;
#pragma unroll
    for (int c2 = 0; c2 < 8; ++c2)
      a += wproj[o * 64 + h * 8 + c2] * attn[((b * 8 + h) * 8 + c2) * 8 + d];
    Epack[idx] = f2bf(a);
  }
}

// ---------------------------------------------------------------------------
// K6: out[b,o,n] = bproj[o] + E[b].v_t  as per-batch MFMA GEMM, fp32 stores.
__global__ __launch_bounds__(256, 4) void k_out(const short* __restrict__ v_t,
    const short* __restrict__ Epack, const float* __restrict__ bproj,
    float* __restrict__ out) {
  const int b = blockIdx.x >> 10, ntile = blockIdx.x & 1023;
  const int wave = threadIdx.x >> 6, lane = threadIdx.x & 63;
  const int quad = lane >> 4, l15 = lane & 15;
  const int n = ntile * 64 + wave * 16 + l15;
  f32x4 acc[4];
#pragma unroll
  for (int mt = 0; mt < 4; ++mt) acc[mt] = (f32x4){0.f, 0.f, 0.f, 0.f};
#pragma unroll
  for (int cc = 0; cc < 2; ++cc) {
    const short8 bf = *(const short8*)(v_t + ((size_t)(b * NN + n)) * 64 + cc * 32 + quad * 8);
#pragma unroll
    for (int mt = 0; mt < 4; ++mt) {
      const short8 af = *(const short8*)(Epack + (((b * 2 + cc) * 4 + mt) * 64 + lane) * 8);
      acc[mt] = __builtin_amdgcn_mfma_f32_16x16x32_bf16(af, bf, acc[mt], 0, 0, 0);
    }
  }
#pragma unroll
  for (int mt = 0; mt < 4; ++mt)
#pragma unroll
    for (int reg = 0; reg < 4; ++reg) {
      const int o = mt * 16 + quad * 4 + reg;
      out[((size_t)(b * 64 + o)) * NN + n] = acc[mt][reg] + bproj[o];
    }
}

// ---------------------------------------------------------------------------
// Workspace (byte offsets), total 134307840 <= proven ws capacity:
//  [0,   64M)  qk bf16 [b][128][N]  -> after k_gram: v_t [0,32M), apw2 @32M
//  [64M, 96M)  x_t bf16 [b][n][64]
//  [96M,128M)  y_t bf16 [b][n][64]
//  [128M, ..)  gram2 32KB | apk 16KB | apm 8KB | Epack 32KB
extern "C" void kernel_launch(void* const* d_in, const int* in_sizes, int n_in,
                              void* d_out, int out_size, void* d_ws, size_t ws_size,
                              hipStream_t stream) {
  const float* x     = (const float*)d_in[0];
  const float* wqkv  = (const float*)d_in[1];
  const float* bqkv  = (const float*)d_in[2];
  const float* wdw   = (const float*)d_in[3];
  const float* bdw   = (const float*)d_in[4];
  const float* wproj = (const float*)d_in[5];
  const float* bproj = (const float*)d_in[6];
  const float* temp  = (const float*)d_in[7];
  const float* wm1   = (const float*)d_in[8];
  const float* gamma = (const float*)d_in[9];
  const float* beta  = (const float*)d_in[10];
  const float* mean  = (const float*)d_in[11];
  const float* var   = (const float*)d_in[12];
  const float* wm2   = (const float*)d_in[13];

  char* wsb = (char*)d_ws;
  short* qk    = (short*)(wsb);
  short* v_t   = (short*)(wsb);                       // aliases qk (after k_gram)
  short* apw2  = (short*)(wsb + 33554432);            // aliases qk tail (after k_gram)
  short* x_t   = (short*)(wsb + 67108864);
  short* y_t   = (short*)(wsb + 100663296);
  float* gram2 = (float*)(wsb + 134217728);
  short* apk   = (short*)(wsb + 134217728 + 32768);
  short* apm   = (short*)(wsb + 134217728 + 49152);
  short* Epack = (short*)(wsb + 134217728 + 57344);
  float* out   = (float*)d_out;

  k_prep1<<<dim3(64), dim3(256), 0, stream>>>(wqkv, wm1, apk, apm, gram2);
  k_xt<<<dim3(1024), dim3(256), 0, stream>>>(x, x_t);
  k_qk1x1<<<dim3(4096), dim3(256), 0, stream>>>(x_t, apk, bqkv, qk);
  k_gram<<<dim3(2048), dim3(256), 0, stream>>>(qk, wdw, bdw, gram2);
  k_prep2<<<dim3(64), dim3(256), 0, stream>>>(wm2, apw2);
  k_m1_bn<<<dim3(4096), dim3(256), 0, stream>>>(x_t, apm, gamma, beta, mean, var, y_t);
  k_conv5<<<dim3(1024), dim3(256), 0, stream>>>(y_t, apw2, x_t, v_t);
  k_attn_e<<<dim3(1), dim3(256), 0, stream>>>(gram2, temp, wproj, Epack);
  k_out<<<dim3(4096), dim3(256), 0, stream>>>(v_t, Epack, bproj, out);
}

// Round 3
// 379.751 us; speedup vs baseline: 1.0416x; 1.0416x over previous
//
#include <hip/hip_runtime.h>
#include <math.h>

#define B 4
#define C 64
#define NN 65536

typedef __attribute__((ext_vector_type(8))) short short8;
typedef __attribute__((ext_vector_type(4))) short short4b;
typedef __attribute__((ext_vector_type(4))) float f32x4;

__device__ inline float bf2f(short s) {
  union { unsigned u; float f; } v; v.u = ((unsigned)(unsigned short)s) << 16; return v.f;
}
__device__ inline short f2bf(float f) {
  union { float f; unsigned u; } v; v.f = f;
  unsigned r = v.u + 0x7FFFu + ((v.u >> 16) & 1u);  // RNE
  return (short)(r >> 16);
}

// ---------------------------------------------------------------------------
// P1: pack w_qkv (first 128 rows) and w_m1 into MFMA A-frag order; zero gram2.
// A-frag (16x16x32): lane l holds A[m=l&15][k=(l>>4)*8+j], j=0..7.
__global__ void k_prep1(const float* __restrict__ wqkv, const float* __restrict__ wm1,
    short* __restrict__ apk, short* __restrict__ apm, float* __restrict__ gram2) {
  for (int idx = blockIdx.x * 256 + threadIdx.x; idx < 20480; idx += 16384) {
    if (idx < 8192) {
      const int j = idx & 7, lane = (idx >> 3) & 63, mt = (idx >> 9) & 7, cc = idx >> 12;
      const int o = mt * 16 + (lane & 15), c = cc * 32 + (lane >> 4) * 8 + j;
      apk[idx] = f2bf(wqkv[o * 64 + c]);
    } else if (idx < 12288) {
      const int k = idx - 8192;
      const int j = k & 7, lane = (k >> 3) & 63, mt = (k >> 9) & 3, cc = k >> 11;
      const int o = mt * 16 + (lane & 15), c = cc * 32 + (lane >> 4) * 8 + j;
      apm[k] = f2bf(wm1[o * 64 + c]);
    } else {
      gram2[idx - 12288] = 0.f;
    }
  }
}

// P2: pack w2 (OIHW 64x64x5x5) -> A-frag order [t][cc][mt][lane][j].
// Launched AFTER k_gram (its buffer aliases the dead qk region).
__global__ void k_prep2(const float* __restrict__ w2, short* __restrict__ apw2) {
  for (int idx = blockIdx.x * 256 + threadIdx.x; idx < 25 * 2 * 4 * 64 * 8; idx += 16384) {
    const int j = idx & 7, lane = (idx >> 3) & 63, mt = (idx >> 9) & 3,
              cc = (idx >> 11) & 1, t = idx >> 12;
    const int o = mt * 16 + (lane & 15);
    const int c = cc * 32 + (lane >> 4) * 8 + j;
    apw2[idx] = f2bf(w2[((size_t)o * 64 + c) * 25 + t]);
  }
}

// ---------------------------------------------------------------------------
// XT: x[b,c,n] fp32 -> x_t[b,n,64] bf16 (channel-innermost) via LDS transpose.
__global__ __launch_bounds__(256) void k_xt(const float* __restrict__ x,
    short* __restrict__ x_t) {
  __shared__ short lds[256 * 72];
  const int b = blockIdx.x >> 8, n0 = (blockIdx.x & 255) << 8;
  const int t = threadIdx.x;
#pragma unroll 4
  for (int c = 0; c < 64; ++c)
    lds[t * 72 + c] = f2bf(x[((size_t)(b * 64 + c)) * NN + n0 + t]);
  __syncthreads();
  short* dst = x_t + ((size_t)(b * NN + n0)) * 64;
#pragma unroll
  for (int it = 0; it < 8; ++it) {
    const int idx = it * 256 + t;
    const int nl = idx >> 3, cb = idx & 7;
    *(short8*)(dst + (size_t)nl * 64 + cb * 8) = *(const short8*)(lds + nl * 72 + cb * 8);
  }
}

// ---------------------------------------------------------------------------
// K1: qk 1x1 conv as MFMA GEMM: qk[b,o<128,n] = wqkv.x + b. B-frag straight
// from x_t (one short8 global load per k-chunk; no LDS).
__global__ __launch_bounds__(256, 4) void k_qk1x1(const short* __restrict__ x_t,
    const short* __restrict__ apk, const float* __restrict__ bias,
    short* __restrict__ qk) {
  const int b = blockIdx.x >> 10, ntile = blockIdx.x & 1023;
  const int wave = threadIdx.x >> 6, lane = threadIdx.x & 63;
  const int quad = lane >> 4, l15 = lane & 15;
  const int n = ntile * 64 + wave * 16 + l15;
  f32x4 acc[8];
#pragma unroll
  for (int mt = 0; mt < 8; ++mt) acc[mt] = (f32x4){0.f, 0.f, 0.f, 0.f};
#pragma unroll
  for (int cc = 0; cc < 2; ++cc) {
    const short8 bf = *(const short8*)(x_t + ((size_t)(b * NN + n)) * 64 + cc * 32 + quad * 8);
#pragma unroll
    for (int mt = 0; mt < 8; ++mt) {
      const short8 af = *(const short8*)(apk + ((cc * 8 + mt) * 64 + lane) * 8);
      acc[mt] = __builtin_amdgcn_mfma_f32_16x16x32_bf16(af, bf, acc[mt], 0, 0, 0);
    }
  }
#pragma unroll
  for (int mt = 0; mt < 8; ++mt)
#pragma unroll
    for (int reg = 0; reg < 4; ++reg) {
      const int o = mt * 16 + quad * 4 + reg;
      qk[((size_t)(b * 128 + o)) * NN + n] = f2bf(acc[mt][reg] + bias[o]);
    }
}

// ---------------------------------------------------------------------------
// K2: FUSED depthwise-3x3 + Gram, latency-optimized.
// Each wave owns one full image row (wave-uniform y): per s-step a lane
// computes 8 dw outputs of its channel (ch = l15 -> 8 q-rows / 8 k-rows of
// head h) from ONE aligned short8 load + 2 predicated edge scalars per tap
// row, then mfma(frag, frag) accumulates S.S^T. 4-wave LDS reduction before
// the global atomics (524K atomics total instead of 2M).
__global__ __launch_bounds__(256, 4) void k_gram(const short* __restrict__ qk,
    const float* __restrict__ wdw, const float* __restrict__ bdw,
    float* __restrict__ gram2) {
  __shared__ float red[4][256];
  const int bh = blockIdx.x >> 6, chunk = blockIdx.x & 63;
  const int b = bh >> 3, h = bh & 7;
  const int wave = threadIdx.x >> 6, lane = threadIdx.x & 63;
  const int quad = lane >> 4, l15 = lane & 15;
  const int ch = (l15 < 8) ? (h * 8 + l15) : (64 + h * 8 + (l15 - 8));
  const short* plane = qk + ((size_t)(b * 128 + ch)) * NN;
  float wreg[9];
#pragma unroll
  for (int i = 0; i < 9; ++i) wreg[i] = wdw[ch * 9 + i];
  const float bias = bdw[ch];
  const int row = chunk * 4 + wave;          // wave-uniform output row 0..255
  const short* prow = plane + row * 256;
  f32x4 acc = {0.f, 0.f, 0.f, 0.f};
  for (int s = 0; s < 8; ++s) {
    const int px0 = s * 32 + quad * 8;       // 8-aligned -> 16B-aligned loads
    float a[8];
#pragma unroll
    for (int j = 0; j < 8; ++j) a[j] = bias;
#pragma unroll
    for (int dy = 0; dy < 3; ++dy) {
      if (dy == 0 && row == 0) continue;     // wave-uniform branches
      if (dy == 2 && row == 255) continue;
      const short* pr = prow + (dy - 1) * 256 + px0;
      const short8 mid = *(const short8*)pr;
      float m[10];
      m[0] = 0.f;
      if (px0 > 0) m[0] = bf2f(pr[-1]);      // predicated: no OOB speculation
      m[9] = 0.f;
      if (px0 < 248) m[9] = bf2f(pr[8]);
#pragma unroll
      for (int k = 0; k < 8; ++k) m[k + 1] = bf2f(mid[k]);
      const float w0 = wreg[dy * 3], w1 = wreg[dy * 3 + 1], w2 = wreg[dy * 3 + 2];
#pragma unroll
      for (int j = 0; j < 8; ++j)
        a[j] = fmaf(w2, m[j + 2], fmaf(w1, m[j + 1], fmaf(w0, m[j], a[j])));
    }
    short8 frag;
#pragma unroll
    for (int j = 0; j < 8; ++j) frag[j] = f2bf(a[j]);
    acc = __builtin_amdgcn_mfma_f32_16x16x32_bf16(frag, frag, acc, 0, 0, 0);
  }
#pragma unroll
  for (int reg = 0; reg < 4; ++reg)
    red[wave][(quad * 4 + reg) * 16 + l15] = acc[reg];
  __syncthreads();
  {
    const int e = threadIdx.x;
    const float s4 = red[0][e] + red[1][e] + red[2][e] + red[3][e];
    atomicAdd(&gram2[bh * 256 + e], s4);
  }
}

// ---------------------------------------------------------------------------
// K3: m1 1x1 conv + BN as MFMA GEMM -> y_t[b,n,64] bf16 via LDS repack.
__global__ __launch_bounds__(256, 4) void k_m1_bn(const short* __restrict__ x_t,
    const short* __restrict__ apm, const float* __restrict__ gamma,
    const float* __restrict__ beta, const float* __restrict__ mean,
    const float* __restrict__ var, short* __restrict__ y_t) {
  __shared__ short lds[64 * 72];
  const int b = blockIdx.x >> 10, ntile = blockIdx.x & 1023;
  const int wave = threadIdx.x >> 6, lane = threadIdx.x & 63;
  const int quad = lane >> 4, l15 = lane & 15;
  const int n = ntile * 64 + wave * 16 + l15;
  f32x4 acc[4];
#pragma unroll
  for (int mt = 0; mt < 4; ++mt) acc[mt] = (f32x4){0.f, 0.f, 0.f, 0.f};
#pragma unroll
  for (int cc = 0; cc < 2; ++cc) {
    const short8 bf = *(const short8*)(x_t + ((size_t)(b * NN + n)) * 64 + cc * 32 + quad * 8);
#pragma unroll
    for (int mt = 0; mt < 4; ++mt) {
      const short8 af = *(const short8*)(apm + ((cc * 4 + mt) * 64 + lane) * 8);
      acc[mt] = __builtin_amdgcn_mfma_f32_16x16x32_bf16(af, bf, acc[mt], 0, 0, 0);
    }
  }
#pragma unroll
  for (int mt = 0; mt < 4; ++mt)
#pragma unroll
    for (int reg = 0; reg < 4; ++reg) {
      const int o = mt * 16 + quad * 4 + reg;
      const float sc = gamma[o] * rsqrtf(var[o] + 1e-5f);
      lds[(wave * 16 + l15) * 72 + o] = f2bf((acc[mt][reg] - mean[o]) * sc + beta[o]);
    }
  __syncthreads();
  short* dst = y_t + ((size_t)(b * NN + ntile * 64)) * 64;
#pragma unroll
  for (int it = 0; it < 2; ++it) {
    const int idx = it * 256 + threadIdx.x;
    const int lcol = idx >> 3, cb = idx & 7;
    *(short8*)(dst + (size_t)lcol * 64 + cb * 8) = *(const short8*)(lds + lcol * 72 + cb * 8);
  }
}

// ---------------------------------------------------------------------------
// K4: conv5x5 implicit-GEMM MFMA, XOR-swizzled staging (conflict-free).
// launch_bounds(256,3): reg budget 512/3=170 >= ~132 needed (64 AGPR acc +
// ~68 VGPR) -> NO SPILL (the (256,4)=128-reg clamp spilled ~110MB of scratch
// writes/kernel). 3 blocks/CU, LDS 3*38.9=116.7KB <= 160KB.
// Staging layout: L = rr*68+col (rr<8, col<68), channel-quad cb (16B each);
// byte = (L*64 + cb*16) ^ (((L>>1)&3)<<4) -- bijective per 8 consecutive L
// per quad -> conflict-free b128 on both ds_write and ds_read.
__global__ __launch_bounds__(256, 3) void k_conv5(const short* __restrict__ y_t,
    const short* __restrict__ apw2, const short* __restrict__ x_t,
    short* __restrict__ v_t) {
  __shared__ short slds[4 * 64 * 76];  // 38,912 B >= staging 34,816 B
  char* sb = (char*)slds;
  const int b = blockIdx.x >> 8;
  const int rg = (blockIdx.x >> 2) & 63, cg = blockIdx.x & 3;
  const int r0 = rg * 4, x0 = cg * 64;
  const int wave = threadIdx.x >> 6, lane = threadIdx.x & 63;
  const int quad = lane >> 4, l15 = lane & 15;
  f32x4 acc[4][4];
#pragma unroll
  for (int mt = 0; mt < 4; ++mt)
#pragma unroll
    for (int nt = 0; nt < 4; ++nt) acc[mt][nt] = (f32x4){0.f, 0.f, 0.f, 0.f};
  for (int cc = 0; cc < 2; ++cc) {
    if (cc) __syncthreads();
    for (int idx = threadIdx.x; idx < 8 * 68 * 4; idx += 256) {
      const int rr = idx / 272, rem = idx - rr * 272;
      const int col = rem >> 2, cb = rem & 3;
      const int gr = r0 - 2 + rr, gc = x0 - 2 + col;
      short8 val = {0, 0, 0, 0, 0, 0, 0, 0};
      if (gr >= 0 && gr < 256 && gc >= 0 && gc < 256)
        val = *(const short8*)(y_t + ((size_t)(b * NN + gr * 256 + gc)) * 64 + cc * 32 + cb * 8);
      const int L = rr * 68 + col;
      *(short8*)(sb + ((L * 64 + cb * 16) ^ (((L >> 1) & 3) << 4))) = val;
    }
    __syncthreads();
    for (int t = 0; t < 25; ++t) {
      const int dy = t / 5 - 2, dx = t % 5 - 2;
      short8 a[4];
#pragma unroll
      for (int mt = 0; mt < 4; ++mt)
        a[mt] = *(const short8*)(apw2 + (((t * 2 + cc) * 4 + mt) * 64 + lane) * 8);
      const int rr = wave + 2 + dy;
#pragma unroll
      for (int nt = 0; nt < 4; ++nt) {
        const int L = rr * 68 + nt * 16 + l15 + 2 + dx;
        const short8 bf =
            *(const short8*)(sb + ((L * 64 + quad * 16) ^ (((L >> 1) & 3) << 4)));
#pragma unroll
        for (int mt = 0; mt < 4; ++mt)
          acc[mt][nt] = __builtin_amdgcn_mfma_f32_16x16x32_bf16(a[mt], bf, acc[mt][nt], 0, 0, 0);
      }
    }
  }
  __syncthreads();  // done reading staging; reuse slds as [row4][col64] stride 76
  const int row = r0 + wave;
#pragma unroll
  for (int nt = 0; nt < 4; ++nt) {
    const int lcol = nt * 16 + l15;
    const short* xp = x_t + ((size_t)(b * NN + row * 256 + x0 + lcol)) * 64 + quad * 4;
#pragma unroll
    for (int mt = 0; mt < 4; ++mt) {
      const short4b xv4 = *(const short4b*)(xp + mt * 16);
      short4b pk;
#pragma unroll
      for (int reg = 0; reg < 4; ++reg) {
        const float sg = 1.f / (1.f + __expf(-acc[mt][nt][reg]));
        pk[reg] = f2bf(bf2f(xv4[reg]) * (1.f + sg));
      }
      *(short4b*)(slds + (wave * 64 + lcol) * 76 + mt * 16 + quad * 4) = pk;
    }
  }
  __syncthreads();
#pragma unroll
  for (int it = 0; it < 8; ++it) {
    const int idx = it * 256 + threadIdx.x;
    const int cb = idx & 7, lcol = (idx >> 3) & 63, rr = idx >> 9;
    *(short8*)(v_t + ((size_t)(b * NN + (r0 + rr) * 256 + x0 + lcol)) * 64 + cb * 8) =
        *(const short8*)(slds + (rr * 64 + lcol) * 76 + cb * 8);
  }
}

// ---------------------------------------------------------------------------
// K5: softmax from gram2, fold wproj, emit E directly in bf16 A-frag order:
// Epack[b][cc][mt][lane][j] with A[m=o][k=cv].
__global__ __launch_bounds__(256) void k_attn_e(const float* __restrict__ gram2,
    const float* __restrict__ temp, const float* __restrict__ wproj,
    short* __restrict__ Epack) {
  __shared__ float attn[2048];
  const int t = threadIdx.x;
  {
    const int b = t >> 6, h = (t >> 3) & 7, c = t & 7;
    const float* g = gram2 + (b * 8 + h) * 256;
    const float qn = fmaxf(sqrtf(g[c * 16 + c]), 1e-12f);
    const float tp = temp[h];
    float row[8];
    float mx = -1e30f;
#pragma unroll
    for (int d = 0; d < 8; ++d) {
      const float kn = fmaxf(sqrtf(g[(8 + d) * 16 + (8 + d)]), 1e-12f);
      row[d] = g[c * 16 + 8 + d] / (qn * kn) * tp;
      mx = fmaxf(mx, row[d]);
    }
    float s = 0.f;
#pragma unroll
    for (int d = 0; d < 8; ++d) { row[d] = __expf(row[d] - mx); s += row[d]; }
    const float inv = 1.f / s;
#pragma unroll
    for (int d = 0; d < 8; ++d) attn[t * 8 + d] = row[d] * inv;
  }
  __syncthreads();
  for (int idx = t; idx < 16384; idx += 256) {
    const int j = idx & 7, lane = (idx >> 3) & 63, mt = (idx >> 9) & 3,
              cc = (idx >> 11) & 1, b = idx >> 12;
    const int o = mt * 16 + (lane & 15);
    const int cv = cc * 32 + (lane >> 4) * 8 + j;
    const int h = cv >> 3, d = cv & 7;
    float a = 0.f;
#pragma unroll
    for (int c2 = 0; c2 < 8; ++c2)
      a += wproj[o * 64 + h * 8 + c2] * attn[((b * 8 + h) * 8 + c2) * 8 + d];
    Epack[idx] = f2bf(a);
  }
}

// ---------------------------------------------------------------------------
// K6: out[b,o,n] = bproj[o] + E[b].v_t  as per-batch MFMA GEMM, fp32 stores.
__global__ __launch_bounds__(256, 4) void k_out(const short* __restrict__ v_t,
    const short* __restrict__ Epack, const float* __restrict__ bproj,
    float* __restrict__ out) {
  const int b = blockIdx.x >> 10, ntile = blockIdx.x & 1023;
  const int wave = threadIdx.x >> 6, lane = threadIdx.x & 63;
  const int quad = lane >> 4, l15 = lane & 15;
  const int n = ntile * 64 + wave * 16 + l15;
  f32x4 acc[4];
#pragma unroll
  for (int mt = 0; mt < 4; ++mt) acc[mt] = (f32x4){0.f, 0.f, 0.f, 0.f};
#pragma unroll
  for (int cc = 0; cc < 2; ++cc) {
    const short8 bf = *(const short8*)(v_t + ((size_t)(b * NN + n)) * 64 + cc * 32 + quad * 8);
#pragma unroll
    for (int mt = 0; mt < 4; ++mt) {
      const short8 af = *(const short8*)(Epack + (((b * 2 + cc) * 4 + mt) * 64 + lane) * 8);
      acc[mt] = __builtin_amdgcn_mfma_f32_16x16x32_bf16(af, bf, acc[mt], 0, 0, 0);
    }
  }
#pragma unroll
  for (int mt = 0; mt < 4; ++mt)
#pragma unroll
    for (int reg = 0; reg < 4; ++reg) {
      const int o = mt * 16 + quad * 4 + reg;
      out[((size_t)(b * 64 + o)) * NN + n] = acc[mt][reg] + bproj[o];
    }
}

// ---------------------------------------------------------------------------
// Workspace (byte offsets), total 134307840 <= proven ws capacity:
//  [0,   64M)  qk bf16 [b][128][N]  -> after k_gram: v_t [0,32M), apw2 @32M
//  [64M, 96M)  x_t bf16 [b][n][64]
//  [96M,128M)  y_t bf16 [b][n][64]
//  [128M, ..)  gram2 32KB | apk 16KB | apm 8KB | Epack 32KB
extern "C" void kernel_launch(void* const* d_in, const int* in_sizes, int n_in,
                              void* d_out, int out_size, void* d_ws, size_t ws_size,
                              hipStream_t stream) {
  const float* x     = (const float*)d_in[0];
  const float* wqkv  = (const float*)d_in[1];
  const float* bqkv  = (const float*)d_in[2];
  const float* wdw   = (const float*)d_in[3];
  const float* bdw   = (const float*)d_in[4];
  const float* wproj = (const float*)d_in[5];
  const float* bproj = (const float*)d_in[6];
  const float* temp  = (const float*)d_in[7];
  const float* wm1   = (const float*)d_in[8];
  const float* gamma = (const float*)d_in[9];
  const float* beta  = (const float*)d_in[10];
  const float* mean  = (const float*)d_in[11];
  const float* var   = (const float*)d_in[12];
  const float* wm2   = (const float*)d_in[13];

  char* wsb = (char*)d_ws;
  short* qk    = (short*)(wsb);
  short* v_t   = (short*)(wsb);                       // aliases qk (after k_gram)
  short* apw2  = (short*)(wsb + 33554432);            // aliases qk tail (after k_gram)
  short* x_t   = (short*)(wsb + 67108864);
  short* y_t   = (short*)(wsb + 100663296);
  float* gram2 = (float*)(wsb + 134217728);
  short* apk   = (short*)(wsb + 134217728 + 32768);
  short* apm   = (short*)(wsb + 134217728 + 49152);
  short* Epack = (short*)(wsb + 134217728 + 57344);
  float* out   = (float*)d_out;

  k_prep1<<<dim3(64), dim3(256), 0, stream>>>(wqkv, wm1, apk, apm, gram2);
  k_xt<<<dim3(1024), dim3(256), 0, stream>>>(x, x_t);
  k_qk1x1<<<dim3(4096), dim3(256), 0, stream>>>(x_t, apk, bqkv, qk);
  k_gram<<<dim3(2048), dim3(256), 0, stream>>>(qk, wdw, bdw, gram2);
  k_prep2<<<dim3(64), dim3(256), 0, stream>>>(wm2, apw2);
  k_m1_bn<<<dim3(4096), dim3(256), 0, stream>>>(x_t, apm, gamma, beta, mean, var, y_t);
  k_conv5<<<dim3(1024), dim3(256), 0, stream>>>(y_t, apw2, x_t, v_t);
  k_attn_e<<<dim3(1), dim3(256), 0, stream>>>(gram2, temp, wproj, Epack);
  k_out<<<dim3(4096), dim3(256), 0, stream>>>(v_t, Epack, bproj, out);
}

// Round 4
// 342.006 us; speedup vs baseline: 1.1566x; 1.1104x over previous
//
#include <hip/hip_runtime.h>
#include <math.h>

#define B 4
#define C 64
#define NN 65536

typedef __attribute__((ext_vector_type(8))) short short8;
typedef __attribute__((ext_vector_type(4))) short short4b;
typedef __attribute__((ext_vector_type(4))) float f32x4;

__device__ inline float bf2f(short s) {
  union { unsigned u; float f; } v; v.u = ((unsigned)(unsigned short)s) << 16; return v.f;
}
__device__ inline short f2bf(float f) {
  union { float f; unsigned u; } v; v.f = f;
  unsigned r = v.u + 0x7FFFu + ((v.u >> 16) & 1u);  // RNE
  return (short)(r >> 16);
}

// ---------------------------------------------------------------------------
// P1: pack w_qkv (first 128 rows) and w_m1 into MFMA A-frag order; zero gram2.
// A-frag (16x16x32): lane l holds A[m=l&15][k=(l>>4)*8+j], j=0..7.
__global__ void k_prep1(const float* __restrict__ wqkv, const float* __restrict__ wm1,
    short* __restrict__ apk, short* __restrict__ apm, float* __restrict__ gram2) {
  for (int idx = blockIdx.x * 256 + threadIdx.x; idx < 20480; idx += 16384) {
    if (idx < 8192) {
      const int j = idx & 7, lane = (idx >> 3) & 63, mt = (idx >> 9) & 7, cc = idx >> 12;
      const int o = mt * 16 + (lane & 15), c = cc * 32 + (lane >> 4) * 8 + j;
      apk[idx] = f2bf(wqkv[o * 64 + c]);
    } else if (idx < 12288) {
      const int k = idx - 8192;
      const int j = k & 7, lane = (k >> 3) & 63, mt = (k >> 9) & 3, cc = k >> 11;
      const int o = mt * 16 + (lane & 15), c = cc * 32 + (lane >> 4) * 8 + j;
      apm[k] = f2bf(wm1[o * 64 + c]);
    } else {
      gram2[idx - 12288] = 0.f;
    }
  }
}

// P2: pack w2 (OIHW 64x64x5x5) -> A-frag order [t][cc][mt][lane][j].
// Launched AFTER k_gram (its buffer aliases the dead qk region).
__global__ void k_prep2(const float* __restrict__ w2, short* __restrict__ apw2) {
  for (int idx = blockIdx.x * 256 + threadIdx.x; idx < 25 * 2 * 4 * 64 * 8; idx += 16384) {
    const int j = idx & 7, lane = (idx >> 3) & 63, mt = (idx >> 9) & 3,
              cc = (idx >> 11) & 1, t = idx >> 12;
    const int o = mt * 16 + (lane & 15);
    const int c = cc * 32 + (lane >> 4) * 8 + j;
    apw2[idx] = f2bf(w2[((size_t)o * 64 + c) * 25 + t]);
  }
}

// ---------------------------------------------------------------------------
// XT: x[b,c,n] fp32 -> x_t[b,n,64] bf16 (channel-innermost) via LDS transpose.
__global__ __launch_bounds__(256) void k_xt(const float* __restrict__ x,
    short* __restrict__ x_t) {
  __shared__ short lds[256 * 72];
  const int b = blockIdx.x >> 8, n0 = (blockIdx.x & 255) << 8;
  const int t = threadIdx.x;
#pragma unroll 4
  for (int c = 0; c < 64; ++c)
    lds[t * 72 + c] = f2bf(x[((size_t)(b * 64 + c)) * NN + n0 + t]);
  __syncthreads();
  short* dst = x_t + ((size_t)(b * NN + n0)) * 64;
#pragma unroll
  for (int it = 0; it < 8; ++it) {
    const int idx = it * 256 + t;
    const int nl = idx >> 3, cb = idx & 7;
    *(short8*)(dst + (size_t)nl * 64 + cb * 8) = *(const short8*)(lds + nl * 72 + cb * 8);
  }
}

// ---------------------------------------------------------------------------
// K1: qk 1x1 conv as MFMA GEMM: qk[b,o<128,n] = wqkv.x + b. B-frag straight
// from x_t (one short8 global load per k-chunk; no LDS).
__global__ __launch_bounds__(256, 4) void k_qk1x1(const short* __restrict__ x_t,
    const short* __restrict__ apk, const float* __restrict__ bias,
    short* __restrict__ qk) {
  const int b = blockIdx.x >> 10, ntile = blockIdx.x & 1023;
  const int wave = threadIdx.x >> 6, lane = threadIdx.x & 63;
  const int quad = lane >> 4, l15 = lane & 15;
  const int n = ntile * 64 + wave * 16 + l15;
  f32x4 acc[8];
#pragma unroll
  for (int mt = 0; mt < 8; ++mt) acc[mt] = (f32x4){0.f, 0.f, 0.f, 0.f};
#pragma unroll
  for (int cc = 0; cc < 2; ++cc) {
    const short8 bf = *(const short8*)(x_t + ((size_t)(b * NN + n)) * 64 + cc * 32 + quad * 8);
#pragma unroll
    for (int mt = 0; mt < 8; ++mt) {
      const short8 af = *(const short8*)(apk + ((cc * 8 + mt) * 64 + lane) * 8);
      acc[mt] = __builtin_amdgcn_mfma_f32_16x16x32_bf16(af, bf, acc[mt], 0, 0, 0);
    }
  }
#pragma unroll
  for (int mt = 0; mt < 8; ++mt)
#pragma unroll
    for (int reg = 0; reg < 4; ++reg) {
      const int o = mt * 16 + quad * 4 + reg;
      qk[((size_t)(b * 128 + o)) * NN + n] = f2bf(acc[mt][reg] + bias[o]);
    }
}

// ---------------------------------------------------------------------------
// K2: FUSED depthwise-3x3 + Gram, latency-optimized.
// Each wave owns one full image row (wave-uniform y): per s-step a lane
// computes 8 dw outputs of its channel (ch = l15 -> 8 q-rows / 8 k-rows of
// head h) from ONE aligned short8 load + 2 predicated edge scalars per tap
// row, then mfma(frag, frag) accumulates S.S^T. 4-wave LDS reduction before
// the global atomics (524K atomics total instead of 2M).
__global__ __launch_bounds__(256, 4) void k_gram(const short* __restrict__ qk,
    const float* __restrict__ wdw, const float* __restrict__ bdw,
    float* __restrict__ gram2) {
  __shared__ float red[4][256];
  const int bh = blockIdx.x >> 6, chunk = blockIdx.x & 63;
  const int b = bh >> 3, h = bh & 7;
  const int wave = threadIdx.x >> 6, lane = threadIdx.x & 63;
  const int quad = lane >> 4, l15 = lane & 15;
  const int ch = (l15 < 8) ? (h * 8 + l15) : (64 + h * 8 + (l15 - 8));
  const short* plane = qk + ((size_t)(b * 128 + ch)) * NN;
  float wreg[9];
#pragma unroll
  for (int i = 0; i < 9; ++i) wreg[i] = wdw[ch * 9 + i];
  const float bias = bdw[ch];
  const int row = chunk * 4 + wave;          // wave-uniform output row 0..255
  const short* prow = plane + row * 256;
  f32x4 acc = {0.f, 0.f, 0.f, 0.f};
  for (int s = 0; s < 8; ++s) {
    const int px0 = s * 32 + quad * 8;       // 8-aligned -> 16B-aligned loads
    float a[8];
#pragma unroll
    for (int j = 0; j < 8; ++j) a[j] = bias;
#pragma unroll
    for (int dy = 0; dy < 3; ++dy) {
      if (dy == 0 && row == 0) continue;     // wave-uniform branches
      if (dy == 2 && row == 255) continue;
      const short* pr = prow + (dy - 1) * 256 + px0;
      const short8 mid = *(const short8*)pr;
      float m[10];
      m[0] = 0.f;
      if (px0 > 0) m[0] = bf2f(pr[-1]);      // predicated: no OOB speculation
      m[9] = 0.f;
      if (px0 < 248) m[9] = bf2f(pr[8]);
#pragma unroll
      for (int k = 0; k < 8; ++k) m[k + 1] = bf2f(mid[k]);
      const float w0 = wreg[dy * 3], w1 = wreg[dy * 3 + 1], w2 = wreg[dy * 3 + 2];
#pragma unroll
      for (int j = 0; j < 8; ++j)
        a[j] = fmaf(w2, m[j + 2], fmaf(w1, m[j + 1], fmaf(w0, m[j], a[j])));
    }
    short8 frag;
#pragma unroll
    for (int j = 0; j < 8; ++j) frag[j] = f2bf(a[j]);
    acc = __builtin_amdgcn_mfma_f32_16x16x32_bf16(frag, frag, acc, 0, 0, 0);
  }
#pragma unroll
  for (int reg = 0; reg < 4; ++reg)
    red[wave][(quad * 4 + reg) * 16 + l15] = acc[reg];
  __syncthreads();
  {
    const int e = threadIdx.x;
    const float s4 = red[0][e] + red[1][e] + red[2][e] + red[3][e];
    atomicAdd(&gram2[bh * 256 + e], s4);
  }
}

// ---------------------------------------------------------------------------
// K3: m1 1x1 conv + BN as MFMA GEMM -> y_t[b,n,64] bf16 via LDS repack.
__global__ __launch_bounds__(256, 4) void k_m1_bn(const short* __restrict__ x_t,
    const short* __restrict__ apm, const float* __restrict__ gamma,
    const float* __restrict__ beta, const float* __restrict__ mean,
    const float* __restrict__ var, short* __restrict__ y_t) {
  __shared__ short lds[64 * 72];
  const int b = blockIdx.x >> 10, ntile = blockIdx.x & 1023;
  const int wave = threadIdx.x >> 6, lane = threadIdx.x & 63;
  const int quad = lane >> 4, l15 = lane & 15;
  const int n = ntile * 64 + wave * 16 + l15;
  f32x4 acc[4];
#pragma unroll
  for (int mt = 0; mt < 4; ++mt) acc[mt] = (f32x4){0.f, 0.f, 0.f, 0.f};
#pragma unroll
  for (int cc = 0; cc < 2; ++cc) {
    const short8 bf = *(const short8*)(x_t + ((size_t)(b * NN + n)) * 64 + cc * 32 + quad * 8);
#pragma unroll
    for (int mt = 0; mt < 4; ++mt) {
      const short8 af = *(const short8*)(apm + ((cc * 4 + mt) * 64 + lane) * 8);
      acc[mt] = __builtin_amdgcn_mfma_f32_16x16x32_bf16(af, bf, acc[mt], 0, 0, 0);
    }
  }
#pragma unroll
  for (int mt = 0; mt < 4; ++mt)
#pragma unroll
    for (int reg = 0; reg < 4; ++reg) {
      const int o = mt * 16 + quad * 4 + reg;
      const float sc = gamma[o] * rsqrtf(var[o] + 1e-5f);
      lds[(wave * 16 + l15) * 72 + o] = f2bf((acc[mt][reg] - mean[o]) * sc + beta[o]);
    }
  __syncthreads();
  short* dst = y_t + ((size_t)(b * NN + ntile * 64)) * 64;
#pragma unroll
  for (int it = 0; it < 2; ++it) {
    const int idx = it * 256 + threadIdx.x;
    const int lcol = idx >> 3, cb = idx & 7;
    *(short8*)(dst + (size_t)lcol * 64 + cb * 8) = *(const short8*)(lds + lcol * 72 + cb * 8);
  }
}

// ---------------------------------------------------------------------------
// K4: conv5x5 implicit-GEMM MFMA, XOR-swizzled staging (conflict-free),
// __launch_bounds__(256,2): 256-reg/wave budget >= ~170 live -> NO SPILL.
// ((256,4) spilled 110MB, (256,3) still spilled 46MB of scratch writes;
// (256,2) + swizzle combines R1's spill-free regs with R2/R3's 0 conflicts.)
// Staging layout: L = rr*68+col (rr<8, col<68), channel-quad cb (16B each);
// byte = (L*64 + cb*16) ^ (((L>>1)&3)<<4) -- bijective per 8 consecutive L
// per quad -> conflict-free b128 on both ds_write and ds_read.
__global__ __launch_bounds__(256, 2) void k_conv5(const short* __restrict__ y_t,
    const short* __restrict__ apw2, const short* __restrict__ x_t,
    short* __restrict__ v_t) {
  __shared__ short slds[4 * 64 * 76];  // 38,912 B >= staging 34,816 B
  char* sb = (char*)slds;
  const int b = blockIdx.x >> 8;
  const int rg = (blockIdx.x >> 2) & 63, cg = blockIdx.x & 3;
  const int r0 = rg * 4, x0 = cg * 64;
  const int wave = threadIdx.x >> 6, lane = threadIdx.x & 63;
  const int quad = lane >> 4, l15 = lane & 15;
  f32x4 acc[4][4];
#pragma unroll
  for (int mt = 0; mt < 4; ++mt)
#pragma unroll
    for (int nt = 0; nt < 4; ++nt) acc[mt][nt] = (f32x4){0.f, 0.f, 0.f, 0.f};
  for (int cc = 0; cc < 2; ++cc) {
    if (cc) __syncthreads();
    for (int idx = threadIdx.x; idx < 8 * 68 * 4; idx += 256) {
      const int rr = idx / 272, rem = idx - rr * 272;
      const int col = rem >> 2, cb = rem & 3;
      const int gr = r0 - 2 + rr, gc = x0 - 2 + col;
      short8 val = {0, 0, 0, 0, 0, 0, 0, 0};
      if (gr >= 0 && gr < 256 && gc >= 0 && gc < 256)
        val = *(const short8*)(y_t + ((size_t)(b * NN + gr * 256 + gc)) * 64 + cc * 32 + cb * 8);
      const int L = rr * 68 + col;
      *(short8*)(sb + ((L * 64 + cb * 16) ^ (((L >> 1) & 3) << 4))) = val;
    }
    __syncthreads();
    for (int t = 0; t < 25; ++t) {
      const int dy = t / 5 - 2, dx = t % 5 - 2;
      short8 a[4];
#pragma unroll
      for (int mt = 0; mt < 4; ++mt)
        a[mt] = *(const short8*)(apw2 + (((t * 2 + cc) * 4 + mt) * 64 + lane) * 8);
      const int rr = wave + 2 + dy;
#pragma unroll
      for (int nt = 0; nt < 4; ++nt) {
        const int L = rr * 68 + nt * 16 + l15 + 2 + dx;
        const short8 bf =
            *(const short8*)(sb + ((L * 64 + quad * 16) ^ (((L >> 1) & 3) << 4)));
#pragma unroll
        for (int mt = 0; mt < 4; ++mt)
          acc[mt][nt] = __builtin_amdgcn_mfma_f32_16x16x32_bf16(a[mt], bf, acc[mt][nt], 0, 0, 0);
      }
    }
  }
  __syncthreads();  // done reading staging; reuse slds as [row4][col64] stride 76
  const int row = r0 + wave;
#pragma unroll
  for (int nt = 0; nt < 4; ++nt) {
    const int lcol = nt * 16 + l15;
    const short* xp = x_t + ((size_t)(b * NN + row * 256 + x0 + lcol)) * 64 + quad * 4;
#pragma unroll
    for (int mt = 0; mt < 4; ++mt) {
      const short4b xv4 = *(const short4b*)(xp + mt * 16);
      short4b pk;
#pragma unroll
      for (int reg = 0; reg < 4; ++reg) {
        const float sg = 1.f / (1.f + __expf(-acc[mt][nt][reg]));
        pk[reg] = f2bf(bf2f(xv4[reg]) * (1.f + sg));
      }
      *(short4b*)(slds + (wave * 64 + lcol) * 76 + mt * 16 + quad * 4) = pk;
    }
  }
  __syncthreads();
#pragma unroll
  for (int it = 0; it < 8; ++it) {
    const int idx = it * 256 + threadIdx.x;
    const int cb = idx & 7, lcol = (idx >> 3) & 63, rr = idx >> 9;
    *(short8*)(v_t + ((size_t)(b * NN + (r0 + rr) * 256 + x0 + lcol)) * 64 + cb * 8) =
        *(const short8*)(slds + (rr * 64 + lcol) * 76 + cb * 8);
  }
}

// ---------------------------------------------------------------------------
// K5: softmax from gram2, fold wproj, emit E directly in bf16 A-frag order:
// Epack[b][cc][mt][lane][j] with A[m=o][k=cv].
__global__ __launch_bounds__(256) void k_attn_e(const float* __restrict__ gram2,
    const float* __restrict__ temp, const float* __restrict__ wproj,
    short* __restrict__ Epack) {
  __shared__ float attn[2048];
  const int t = threadIdx.x;
  {
    const int b = t >> 6, h = (t >> 3) & 7, c = t & 7;
    const float* g = gram2 + (b * 8 + h) * 256;
    const float qn = fmaxf(sqrtf(g[c * 16 + c]), 1e-12f);
    const float tp = temp[h];
    float row[8];
    float mx = -1e30f;
#pragma unroll
    for (int d = 0; d < 8; ++d) {
      const float kn = fmaxf(sqrtf(g[(8 + d) * 16 + (8 + d)]), 1e-12f);
      row[d] = g[c * 16 + 8 + d] / (qn * kn) * tp;
      mx = fmaxf(mx, row[d]);
    }
    float s = 0.f;
#pragma unroll
    for (int d = 0; d < 8; ++d) { row[d] = __expf(row[d] - mx); s += row[d]; }
    const float inv = 1.f / s;
#pragma unroll
    for (int d = 0; d < 8; ++d) attn[t * 8 + d] = row[d] * inv;
  }
  __syncthreads();
  for (int idx = t; idx < 16384; idx += 256) {
    const int j = idx & 7, lane = (idx >> 3) & 63, mt = (idx >> 9) & 3,
              cc = (idx >> 11) & 1, b = idx >> 12;
    const int o = mt * 16 + (lane & 15);
    const int cv = cc * 32 + (lane >> 4) * 8 + j;
    const int h = cv >> 3, d = cv & 7;
    float a = 0.f;
#pragma unroll
    for (int c2 = 0; c2 < 8; ++c2)
      a += wproj[o * 64 + h * 8 + c2] * attn[((b * 8 + h) * 8 + c2) * 8 + d];
    Epack[idx] = f2bf(a);
  }
}

// ---------------------------------------------------------------------------
// K6: out[b,o,n] = bproj[o] + E[b].v_t  as per-batch MFMA GEMM, fp32 stores.
__global__ __launch_bounds__(256, 4) void k_out(const short* __restrict__ v_t,
    const short* __restrict__ Epack, const float* __restrict__ bproj,
    float* __restrict__ out) {
  const int b = blockIdx.x >> 10, ntile = blockIdx.x & 1023;
  const int wave = threadIdx.x >> 6, lane = threadIdx.x & 63;
  const int quad = lane >> 4, l15 = lane & 15;
  const int n = ntile * 64 + wave * 16 + l15;
  f32x4 acc[4];
#pragma unroll
  for (int mt = 0; mt < 4; ++mt) acc[mt] = (f32x4){0.f, 0.f, 0.f, 0.f};
#pragma unroll
  for (int cc = 0; cc < 2; ++cc) {
    const short8 bf = *(const short8*)(v_t + ((size_t)(b * NN + n)) * 64 + cc * 32 + quad * 8);
#pragma unroll
    for (int mt = 0; mt < 4; ++mt) {
      const short8 af = *(const short8*)(Epack + (((b * 2 + cc) * 4 + mt) * 64 + lane) * 8);
      acc[mt] = __builtin_amdgcn_mfma_f32_16x16x32_bf16(af, bf, acc[mt], 0, 0, 0);
    }
  }
#pragma unroll
  for (int mt = 0; mt < 4; ++mt)
#pragma unroll
    for (int reg = 0; reg < 4; ++reg) {
      const int o = mt * 16 + quad * 4 + reg;
      out[((size_t)(b * 64 + o)) * NN + n] = acc[mt][reg] + bproj[o];
    }
}

// ---------------------------------------------------------------------------
// Workspace (byte offsets), total 134307840 <= proven ws capacity:
//  [0,   64M)  qk bf16 [b][128][N]  -> after k_gram: v_t [0,32M), apw2 @32M
//  [64M, 96M)  x_t bf16 [b][n][64]
//  [96M,128M)  y_t bf16 [b][n][64]
//  [128M, ..)  gram2 32KB | apk 16KB | apm 8KB | Epack 32KB
extern "C" void kernel_launch(void* const* d_in, const int* in_sizes, int n_in,
                              void* d_out, int out_size, void* d_ws, size_t ws_size,
                              hipStream_t stream) {
  const float* x     = (const float*)d_in[0];
  const float* wqkv  = (const float*)d_in[1];
  const float* bqkv  = (const float*)d_in[2];
  const float* wdw   = (const float*)d_in[3];
  const float* bdw   = (const float*)d_in[4];
  const float* wproj = (const float*)d_in[5];
  const float* bproj = (const float*)d_in[6];
  const float* temp  = (const float*)d_in[7];
  const float* wm1   = (const float*)d_in[8];
  const float* gamma = (const float*)d_in[9];
  const float* beta  = (const float*)d_in[10];
  const float* mean  = (const float*)d_in[11];
  const float* var   = (const float*)d_in[12];
  const float* wm2   = (const float*)d_in[13];

  char* wsb = (char*)d_ws;
  short* qk    = (short*)(wsb);
  short* v_t   = (short*)(wsb);                       // aliases qk (after k_gram)
  short* apw2  = (short*)(wsb + 33554432);            // aliases qk tail (after k_gram)
  short* x_t   = (short*)(wsb + 67108864);
  short* y_t   = (short*)(wsb + 100663296);
  float* gram2 = (float*)(wsb + 134217728);
  short* apk   = (short*)(wsb + 134217728 + 32768);
  short* apm   = (short*)(wsb + 134217728 + 49152);
  short* Epack = (short*)(wsb + 134217728 + 57344);
  float* out   = (float*)d_out;

  k_prep1<<<dim3(64), dim3(256), 0, stream>>>(wqkv, wm1, apk, apm, gram2);
  k_xt<<<dim3(1024), dim3(256), 0, stream>>>(x, x_t);
  k_qk1x1<<<dim3(4096), dim3(256), 0, stream>>>(x_t, apk, bqkv, qk);
  k_gram<<<dim3(2048), dim3(256), 0, stream>>>(qk, wdw, bdw, gram2);
  k_prep2<<<dim3(64), dim3(256), 0, stream>>>(wm2, apw2);
  k_m1_bn<<<dim3(4096), dim3(256), 0, stream>>>(x_t, apm, gamma, beta, mean, var, y_t);
  k_conv5<<<dim3(1024), dim3(256), 0, stream>>>(y_t, apw2, x_t, v_t);
  k_attn_e<<<dim3(1), dim3(256), 0, stream>>>(gram2, temp, wproj, Epack);
  k_out<<<dim3(4096), dim3(256), 0, stream>>>(v_t, Epack, bproj, out);
}

// Round 5
// 308.104 us; speedup vs baseline: 1.2838x; 1.1100x over previous
//
#include <hip/hip_runtime.h>
#include <math.h>

#define B 4
#define C 64
#define NN 65536

typedef __attribute__((ext_vector_type(8))) short short8;
typedef __attribute__((ext_vector_type(4))) short short4b;
typedef __attribute__((ext_vector_type(4))) float f32x4;
typedef __attribute__((ext_vector_type(4))) unsigned int u32x4;

__device__ inline float bf2f(short s) {
  union { unsigned u; float f; } v; v.u = ((unsigned)(unsigned short)s) << 16; return v.f;
}
__device__ inline short f2bf(float f) {
  union { float f; unsigned u; } v; v.f = f;
  unsigned r = v.u + 0x7FFFu + ((v.u >> 16) & 1u);  // RNE
  return (short)(r >> 16);
}
// bf16 pair unpack: low half / high half of a 32-bit word.
__device__ inline float lof(unsigned u) {
  union { unsigned u; float f; } v; v.u = u << 16; return v.f;
}
__device__ inline float hif(unsigned u) {
  union { unsigned u; float f; } v; v.u = u & 0xffff0000u; return v.f;
}

// ---------------------------------------------------------------------------
// P1: pack w_qkv (first 128 rows) and w_m1 into MFMA A-frag order; zero gram2.
// A-frag (16x16x32): lane l holds A[m=l&15][k=(l>>4)*8+j], j=0..7.
__global__ void k_prep1(const float* __restrict__ wqkv, const float* __restrict__ wm1,
    short* __restrict__ apk, short* __restrict__ apm, float* __restrict__ gram2) {
  for (int idx = blockIdx.x * 256 + threadIdx.x; idx < 20480; idx += 16384) {
    if (idx < 8192) {
      const int j = idx & 7, lane = (idx >> 3) & 63, mt = (idx >> 9) & 7, cc = idx >> 12;
      const int o = mt * 16 + (lane & 15), c = cc * 32 + (lane >> 4) * 8 + j;
      apk[idx] = f2bf(wqkv[o * 64 + c]);
    } else if (idx < 12288) {
      const int k = idx - 8192;
      const int j = k & 7, lane = (k >> 3) & 63, mt = (k >> 9) & 3, cc = k >> 11;
      const int o = mt * 16 + (lane & 15), c = cc * 32 + (lane >> 4) * 8 + j;
      apm[k] = f2bf(wm1[o * 64 + c]);
    } else {
      gram2[idx - 12288] = 0.f;
    }
  }
}

// P2: pack w2 (OIHW 64x64x5x5) -> A-frag order [t][cc][mt][lane][j].
// Launched AFTER k_gram (its buffer aliases the dead qk region).
__global__ void k_prep2(const float* __restrict__ w2, short* __restrict__ apw2) {
  for (int idx = blockIdx.x * 256 + threadIdx.x; idx < 25 * 2 * 4 * 64 * 8; idx += 16384) {
    const int j = idx & 7, lane = (idx >> 3) & 63, mt = (idx >> 9) & 3,
              cc = (idx >> 11) & 1, t = idx >> 12;
    const int o = mt * 16 + (lane & 15);
    const int c = cc * 32 + (lane >> 4) * 8 + j;
    apw2[idx] = f2bf(w2[((size_t)o * 64 + c) * 25 + t]);
  }
}

// ---------------------------------------------------------------------------
// XT: x[b,c,n] fp32 -> x_t[b,n,64] bf16 (channel-innermost) via LDS transpose.
__global__ __launch_bounds__(256) void k_xt(const float* __restrict__ x,
    short* __restrict__ x_t) {
  __shared__ short lds[256 * 72];
  const int b = blockIdx.x >> 8, n0 = (blockIdx.x & 255) << 8;
  const int t = threadIdx.x;
#pragma unroll 4
  for (int c = 0; c < 64; ++c)
    lds[t * 72 + c] = f2bf(x[((size_t)(b * 64 + c)) * NN + n0 + t]);
  __syncthreads();
  short* dst = x_t + ((size_t)(b * NN + n0)) * 64;
#pragma unroll
  for (int it = 0; it < 8; ++it) {
    const int idx = it * 256 + t;
    const int nl = idx >> 3, cb = idx & 7;
    *(short8*)(dst + (size_t)nl * 64 + cb * 8) = *(const short8*)(lds + nl * 72 + cb * 8);
  }
}

// ---------------------------------------------------------------------------
// K1: qk 1x1 conv as MFMA GEMM: qk[b,o<128,n] = wqkv.x + b. B-frag straight
// from x_t (one short8 global load per k-chunk; no LDS).
__global__ __launch_bounds__(256, 4) void k_qk1x1(const short* __restrict__ x_t,
    const short* __restrict__ apk, const float* __restrict__ bias,
    short* __restrict__ qk) {
  const int b = blockIdx.x >> 10, ntile = blockIdx.x & 1023;
  const int wave = threadIdx.x >> 6, lane = threadIdx.x & 63;
  const int quad = lane >> 4, l15 = lane & 15;
  const int n = ntile * 64 + wave * 16 + l15;
  f32x4 acc[8];
#pragma unroll
  for (int mt = 0; mt < 8; ++mt) acc[mt] = (f32x4){0.f, 0.f, 0.f, 0.f};
#pragma unroll
  for (int cc = 0; cc < 2; ++cc) {
    const short8 bf = *(const short8*)(x_t + ((size_t)(b * NN + n)) * 64 + cc * 32 + quad * 8);
#pragma unroll
    for (int mt = 0; mt < 8; ++mt) {
      const short8 af = *(const short8*)(apk + ((cc * 8 + mt) * 64 + lane) * 8);
      acc[mt] = __builtin_amdgcn_mfma_f32_16x16x32_bf16(af, bf, acc[mt], 0, 0, 0);
    }
  }
#pragma unroll
  for (int mt = 0; mt < 8; ++mt)
#pragma unroll
    for (int reg = 0; reg < 4; ++reg) {
      const int o = mt * 16 + quad * 4 + reg;
      qk[((size_t)(b * 128 + o)) * NN + n] = f2bf(acc[mt][reg] + bias[o]);
    }
}

// ---------------------------------------------------------------------------
// K2: FUSED depthwise-3x3 + Gram, ILP-optimized.
// All 24 b128 mid-loads (3 dy-rows x 8 s-chunks) are hoisted into registers
// up front -> ONE global latency round-trip instead of 24 serial ones (the
// VGPR=28 round-4 codegen serialized load->use per dy). Edge pixels
// (px0-1, px0+8) come from the hoisted data via __shfl (neighbor quad's
// elem7/elem0, or same-lane adjacent s-chunk) -- no scalar global loads.
// Numerics bit-identical: same values, same fma order, same MFMA.
__global__ __launch_bounds__(256, 3) void k_gram(const short* __restrict__ qk,
    const float* __restrict__ wdw, const float* __restrict__ bdw,
    float* __restrict__ gram2) {
  __shared__ float red[4][256];
  const int bh = blockIdx.x >> 6, chunk = blockIdx.x & 63;
  const int b = bh >> 3, h = bh & 7;
  const int wave = threadIdx.x >> 6, lane = threadIdx.x & 63;
  const int quad = lane >> 4, l15 = lane & 15;
  const int ch = (l15 < 8) ? (h * 8 + l15) : (64 + h * 8 + (l15 - 8));
  const short* plane = qk + ((size_t)(b * 128 + ch)) * NN;
  float wreg[9];
#pragma unroll
  for (int i = 0; i < 9; ++i) wreg[i] = wdw[ch * 9 + i];
  const float bias = bdw[ch];
  const int row = chunk * 4 + wave;          // wave-uniform output row 0..255
  const short* prow = plane + row * 256;
  // Hoisted row buffer: rb[dy][s] = 8 bf16 at px [32s+8q .. 32s+8q+7].
  u32x4 rb[3][8];
#pragma unroll
  for (int dy = 0; dy < 3; ++dy) {
    if (dy == 0 && row == 0) continue;       // wave-uniform
    if (dy == 2 && row == 255) continue;
    const short* pr = prow + (dy - 1) * 256 + quad * 8;
#pragma unroll
    for (int s = 0; s < 8; ++s)
      rb[dy][s] = *(const u32x4*)(pr + s * 32);
  }
  f32x4 acc = {0.f, 0.f, 0.f, 0.f};
#pragma unroll
  for (int s = 0; s < 8; ++s) {
    float a[8];
#pragma unroll
    for (int j = 0; j < 8; ++j) a[j] = bias;
#pragma unroll
    for (int dy = 0; dy < 3; ++dy) {
      if (dy == 0 && row == 0) continue;     // wave-uniform (shfls stay full-wave)
      if (dy == 2 && row == 255) continue;
      const unsigned w0_ = rb[dy][s][0], w1_ = rb[dy][s][1],
                     w2_ = rb[dy][s][2], w3_ = rb[dy][s][3];
      float m[10];
      m[1] = lof(w0_); m[2] = hif(w0_);
      m[3] = lof(w1_); m[4] = hif(w1_);
      m[5] = lof(w2_); m[6] = hif(w2_);
      m[7] = lof(w3_); m[8] = hif(w3_);
      // m[0] = px0-1: elem7 of chunk (s, q-1) [lane-16], or (s-1, q=3) for q==0.
      const unsigned A3 = (unsigned)__shfl((int)w3_, (lane - 16) & 63, 64);
      // m[9] = px0+8: elem0 of chunk (s, q+1) [lane+16], or (s+1, q=0) for q==3.
      const unsigned A0 = (unsigned)__shfl((int)w0_, (lane + 16) & 63, 64);
      float m0q0 = 0.f, m9q3 = 0.f;
      if (s > 0) {   // compile-time after unroll; shfl executed by all lanes
        const unsigned B3 = (unsigned)__shfl((int)rb[dy][s - 1][3], (lane + 48) & 63, 64);
        m0q0 = hif(B3);
      }
      if (s < 7) {
        const unsigned B0 = (unsigned)__shfl((int)rb[dy][s + 1][0], (lane - 48) & 63, 64);
        m9q3 = lof(B0);
      }
      m[0] = (quad == 0) ? m0q0 : hif(A3);
      m[9] = (quad == 3) ? m9q3 : lof(A0);
      const float W0 = wreg[dy * 3], W1 = wreg[dy * 3 + 1], W2 = wreg[dy * 3 + 2];
#pragma unroll
      for (int j = 0; j < 8; ++j)
        a[j] = fmaf(W2, m[j + 2], fmaf(W1, m[j + 1], fmaf(W0, m[j], a[j])));
    }
    short8 frag;
#pragma unroll
    for (int j = 0; j < 8; ++j) frag[j] = f2bf(a[j]);
    acc = __builtin_amdgcn_mfma_f32_16x16x32_bf16(frag, frag, acc, 0, 0, 0);
  }
#pragma unroll
  for (int reg = 0; reg < 4; ++reg)
    red[wave][(quad * 4 + reg) * 16 + l15] = acc[reg];
  __syncthreads();
  {
    const int e = threadIdx.x;
    const float s4 = red[0][e] + red[1][e] + red[2][e] + red[3][e];
    atomicAdd(&gram2[bh * 256 + e], s4);
  }
}

// ---------------------------------------------------------------------------
// K3: m1 1x1 conv + BN as MFMA GEMM -> y_t[b,n,64] bf16 via LDS repack.
__global__ __launch_bounds__(256, 4) void k_m1_bn(const short* __restrict__ x_t,
    const short* __restrict__ apm, const float* __restrict__ gamma,
    const float* __restrict__ beta, const float* __restrict__ mean,
    const float* __restrict__ var, short* __restrict__ y_t) {
  __shared__ short lds[64 * 72];
  const int b = blockIdx.x >> 10, ntile = blockIdx.x & 1023;
  const int wave = threadIdx.x >> 6, lane = threadIdx.x & 63;
  const int quad = lane >> 4, l15 = lane & 15;
  const int n = ntile * 64 + wave * 16 + l15;
  f32x4 acc[4];
#pragma unroll
  for (int mt = 0; mt < 4; ++mt) acc[mt] = (f32x4){0.f, 0.f, 0.f, 0.f};
#pragma unroll
  for (int cc = 0; cc < 2; ++cc) {
    const short8 bf = *(const short8*)(x_t + ((size_t)(b * NN + n)) * 64 + cc * 32 + quad * 8);
#pragma unroll
    for (int mt = 0; mt < 4; ++mt) {
      const short8 af = *(const short8*)(apm + ((cc * 4 + mt) * 64 + lane) * 8);
      acc[mt] = __builtin_amdgcn_mfma_f32_16x16x32_bf16(af, bf, acc[mt], 0, 0, 0);
    }
  }
#pragma unroll
  for (int mt = 0; mt < 4; ++mt)
#pragma unroll
    for (int reg = 0; reg < 4; ++reg) {
      const int o = mt * 16 + quad * 4 + reg;
      const float sc = gamma[o] * rsqrtf(var[o] + 1e-5f);
      lds[(wave * 16 + l15) * 72 + o] = f2bf((acc[mt][reg] - mean[o]) * sc + beta[o]);
    }
  __syncthreads();
  short* dst = y_t + ((size_t)(b * NN + ntile * 64)) * 64;
#pragma unroll
  for (int it = 0; it < 2; ++it) {
    const int idx = it * 256 + threadIdx.x;
    const int lcol = idx >> 3, cb = idx & 7;
    *(short8*)(dst + (size_t)lcol * 64 + cb * 8) = *(const short8*)(lds + lcol * 72 + cb * 8);
  }
}

// ---------------------------------------------------------------------------
// K4: conv5x5 implicit-GEMM MFMA, XOR-swizzled staging (conflict-free),
// __launch_bounds__(256,2): 256-reg/wave budget >= ~170 live -> NO SPILL.
// ((256,4) spilled 110MB, (256,3) still spilled 46MB of scratch writes;
// (256,2) + swizzle combines R1's spill-free regs with R2/R3's 0 conflicts.)
// Staging layout: L = rr*68+col (rr<8, col<68), channel-quad cb (16B each);
// byte = (L*64 + cb*16) ^ (((L>>1)&3)<<4) -- bijective per 8 consecutive L
// per quad -> conflict-free b128 on both ds_write and ds_read.
__global__ __launch_bounds__(256, 2) void k_conv5(const short* __restrict__ y_t,
    const short* __restrict__ apw2, const short* __restrict__ x_t,
    short* __restrict__ v_t) {
  __shared__ short slds[4 * 64 * 76];  // 38,912 B >= staging 34,816 B
  char* sb = (char*)slds;
  const int b = blockIdx.x >> 8;
  const int rg = (blockIdx.x >> 2) & 63, cg = blockIdx.x & 3;
  const int r0 = rg * 4, x0 = cg * 64;
  const int wave = threadIdx.x >> 6, lane = threadIdx.x & 63;
  const int quad = lane >> 4, l15 = lane & 15;
  f32x4 acc[4][4];
#pragma unroll
  for (int mt = 0; mt < 4; ++mt)
#pragma unroll
    for (int nt = 0; nt < 4; ++nt) acc[mt][nt] = (f32x4){0.f, 0.f, 0.f, 0.f};
  for (int cc = 0; cc < 2; ++cc) {
    if (cc) __syncthreads();
    for (int idx = threadIdx.x; idx < 8 * 68 * 4; idx += 256) {
      const int rr = idx / 272, rem = idx - rr * 272;
      const int col = rem >> 2, cb = rem & 3;
      const int gr = r0 - 2 + rr, gc = x0 - 2 + col;
      short8 val = {0, 0, 0, 0, 0, 0, 0, 0};
      if (gr >= 0 && gr < 256 && gc >= 0 && gc < 256)
        val = *(const short8*)(y_t + ((size_t)(b * NN + gr * 256 + gc)) * 64 + cc * 32 + cb * 8);
      const int L = rr * 68 + col;
      *(short8*)(sb + ((L * 64 + cb * 16) ^ (((L >> 1) & 3) << 4))) = val;
    }
    __syncthreads();
    for (int t = 0; t < 25; ++t) {
      const int dy = t / 5 - 2, dx = t % 5 - 2;
      short8 a[4];
#pragma unroll
      for (int mt = 0; mt < 4; ++mt)
        a[mt] = *(const short8*)(apw2 + (((t * 2 + cc) * 4 + mt) * 64 + lane) * 8);
      const int rr = wave + 2 + dy;
#pragma unroll
      for (int nt = 0; nt < 4; ++nt) {
        const int L = rr * 68 + nt * 16 + l15 + 2 + dx;
        const short8 bf =
            *(const short8*)(sb + ((L * 64 + quad * 16) ^ (((L >> 1) & 3) << 4)));
#pragma unroll
        for (int mt = 0; mt < 4; ++mt)
          acc[mt][nt] = __builtin_amdgcn_mfma_f32_16x16x32_bf16(a[mt], bf, acc[mt][nt], 0, 0, 0);
      }
    }
  }
  __syncthreads();  // done reading staging; reuse slds as [row4][col64] stride 76
  const int row = r0 + wave;
#pragma unroll
  for (int nt = 0; nt < 4; ++nt) {
    const int lcol = nt * 16 + l15;
    const short* xp = x_t + ((size_t)(b * NN + row * 256 + x0 + lcol)) * 64 + quad * 4;
#pragma unroll
    for (int mt = 0; mt < 4; ++mt) {
      const short4b xv4 = *(const short4b*)(xp + mt * 16);
      short4b pk;
#pragma unroll
      for (int reg = 0; reg < 4; ++reg) {
        const float sg = 1.f / (1.f + __expf(-acc[mt][nt][reg]));
        pk[reg] = f2bf(bf2f(xv4[reg]) * (1.f + sg));
      }
      *(short4b*)(slds + (wave * 64 + lcol) * 76 + mt * 16 + quad * 4) = pk;
    }
  }
  __syncthreads();
#pragma unroll
  for (int it = 0; it < 8; ++it) {
    const int idx = it * 256 + threadIdx.x;
    const int cb = idx & 7, lcol = (idx >> 3) & 63, rr = idx >> 9;
    *(short8*)(v_t + ((size_t)(b * NN + (r0 + rr) * 256 + x0 + lcol)) * 64 + cb * 8) =
        *(const short8*)(slds + (rr * 64 + lcol) * 76 + cb * 8);
  }
}

// ---------------------------------------------------------------------------
// K5: softmax from gram2, fold wproj, emit E directly in bf16 A-frag order:
// Epack[b][cc][mt][lane][j] with A[m=o][k=cv].
__global__ __launch_bounds__(256) void k_attn_e(const float* __restrict__ gram2,
    const float* __restrict__ temp, const float* __restrict__ wproj,
    short* __restrict__ Epack) {
  __shared__ float attn[2048];
  const int t = threadIdx.x;
  {
    const int b = t >> 6, h = (t >> 3) & 7, c = t & 7;
    const float* g = gram2 + (b * 8 + h) * 256;
    const float qn = fmaxf(sqrtf(g[c * 16 + c]), 1e-12f);
    const float tp = temp[h];
    float row[8];
    float mx = -1e30f;
#pragma unroll
    for (int d = 0; d < 8; ++d) {
      const float kn = fmaxf(sqrtf(g[(8 + d) * 16 + (8 + d)]), 1e-12f);
      row[d] = g[c * 16 + 8 + d] / (qn * kn) * tp;
      mx = fmaxf(mx, row[d]);
    }
    float s = 0.f;
#pragma unroll
    for (int d = 0; d < 8; ++d) { row[d] = __expf(row[d] - mx); s += row[d]; }
    const float inv = 1.f / s;
#pragma unroll
    for (int d = 0; d < 8; ++d) attn[t * 8 + d] = row[d] * inv;
  }
  __syncthreads();
  for (int idx = t; idx < 16384; idx += 256) {
    const int j = idx & 7, lane = (idx >> 3) & 63, mt = (idx >> 9) & 3,
              cc = (idx >> 11) & 1, b = idx >> 12;
    const int o = mt * 16 + (lane & 15);
    const int cv = cc * 32 + (lane >> 4) * 8 + j;
    const int h = cv >> 3, d = cv & 7;
    float a = 0.f;
#pragma unroll
    for (int c2 = 0; c2 < 8; ++c2)
      a += wproj[o * 64 + h * 8 + c2] * attn[((b * 8 + h) * 8 + c2) * 8 + d];
    Epack[idx] = f2bf(a);
  }
}

// ---------------------------------------------------------------------------
// K6: out[b,o,n] = bproj[o] + E[b].v_t  as per-batch MFMA GEMM, fp32 stores.
__global__ __launch_bounds__(256, 4) void k_out(const short* __restrict__ v_t,
    const short* __restrict__ Epack, const float* __restrict__ bproj,
    float* __restrict__ out) {
  const int b = blockIdx.x >> 10, ntile = blockIdx.x & 1023;
  const int wave = threadIdx.x >> 6, lane = threadIdx.x & 63;
  const int quad = lane >> 4, l15 = lane & 15;
  const int n = ntile * 64 + wave * 16 + l15;
  f32x4 acc[4];
#pragma unroll
  for (int mt = 0; mt < 4; ++mt) acc[mt] = (f32x4){0.f, 0.f, 0.f, 0.f};
#pragma unroll
  for (int cc = 0; cc < 2; ++cc) {
    const short8 bf = *(const short8*)(v_t + ((size_t)(b * NN + n)) * 64 + cc * 32 + quad * 8);
#pragma unroll
    for (int mt = 0; mt < 4; ++mt) {
      const short8 af = *(const short8*)(Epack + (((b * 2 + cc) * 4 + mt) * 64 + lane) * 8);
      acc[mt] = __builtin_amdgcn_mfma_f32_16x16x32_bf16(af, bf, acc[mt], 0, 0, 0);
    }
  }
#pragma unroll
  for (int mt = 0; mt < 4; ++mt)
#pragma unroll
    for (int reg = 0; reg < 4; ++reg) {
      const int o = mt * 16 + quad * 4 + reg;
      out[((size_t)(b * 64 + o)) * NN + n] = acc[mt][reg] + bproj[o];
    }
}

// ---------------------------------------------------------------------------
// Workspace (byte offsets), total 134307840 <= proven ws capacity:
//  [0,   64M)  qk bf16 [b][128][N]  -> after k_gram: v_t [0,32M), apw2 @32M
//  [64M, 96M)  x_t bf16 [b][n][64]
//  [96M,128M)  y_t bf16 [b][n][64]
//  [128M, ..)  gram2 32KB | apk 16KB | apm 8KB | Epack 32KB
extern "C" void kernel_launch(void* const* d_in, const int* in_sizes, int n_in,
                              void* d_out, int out_size, void* d_ws, size_t ws_size,
                              hipStream_t stream) {
  const float* x     = (const float*)d_in[0];
  const float* wqkv  = (const float*)d_in[1];
  const float* bqkv  = (const float*)d_in[2];
  const float* wdw   = (const float*)d_in[3];
  const float* bdw   = (const float*)d_in[4];
  const float* wproj = (const float*)d_in[5];
  const float* bproj = (const float*)d_in[6];
  const float* temp  = (const float*)d_in[7];
  const float* wm1   = (const float*)d_in[8];
  const float* gamma = (const float*)d_in[9];
  const float* beta  = (const float*)d_in[10];
  const float* mean  = (const float*)d_in[11];
  const float* var   = (const float*)d_in[12];
  const float* wm2   = (const float*)d_in[13];

  char* wsb = (char*)d_ws;
  short* qk    = (short*)(wsb);
  short* v_t   = (short*)(wsb);                       // aliases qk (after k_gram)
  short* apw2  = (short*)(wsb + 33554432);            // aliases qk tail (after k_gram)
  short* x_t   = (short*)(wsb + 67108864);
  short* y_t   = (short*)(wsb + 100663296);
  float* gram2 = (float*)(wsb + 134217728);
  short* apk   = (short*)(wsb + 134217728 + 32768);
  short* apm   = (short*)(wsb + 134217728 + 49152);
  short* Epack = (short*)(wsb + 134217728 + 57344);
  float* out   = (float*)d_out;

  k_prep1<<<dim3(64), dim3(256), 0, stream>>>(wqkv, wm1, apk, apm, gram2);
  k_xt<<<dim3(1024), dim3(256), 0, stream>>>(x, x_t);
  k_qk1x1<<<dim3(4096), dim3(256), 0, stream>>>(x_t, apk, bqkv, qk);
  k_gram<<<dim3(2048), dim3(256), 0, stream>>>(qk, wdw, bdw, gram2);
  k_prep2<<<dim3(64), dim3(256), 0, stream>>>(wm2, apw2);
  k_m1_bn<<<dim3(4096), dim3(256), 0, stream>>>(x_t, apm, gamma, beta, mean, var, y_t);
  k_conv5<<<dim3(1024), dim3(256), 0, stream>>>(y_t, apw2, x_t, v_t);
  k_attn_e<<<dim3(1), dim3(256), 0, stream>>>(gram2, temp, wproj, Epack);
  k_out<<<dim3(4096), dim3(256), 0, stream>>>(v_t, Epack, bproj, out);
}

// Round 6
// 305.035 us; speedup vs baseline: 1.2967x; 1.0101x over previous
//
#include <hip/hip_runtime.h>
#include <math.h>

#define B 4
#define C 64
#define NN 65536

typedef __attribute__((ext_vector_type(8))) short short8;
typedef __attribute__((ext_vector_type(4))) short short4b;
typedef __attribute__((ext_vector_type(4))) float f32x4;
typedef __attribute__((ext_vector_type(4))) unsigned int u32x4;

__device__ inline float bf2f(short s) {
  union { unsigned u; float f; } v; v.u = ((unsigned)(unsigned short)s) << 16; return v.f;
}
__device__ inline short f2bf(float f) {
  union { float f; unsigned u; } v; v.f = f;
  unsigned r = v.u + 0x7FFFu + ((v.u >> 16) & 1u);  // RNE
  return (short)(r >> 16);
}
// bf16 pair unpack: low half / high half of a 32-bit word.
__device__ inline float lof(unsigned u) {
  union { unsigned u; float f; } v; v.u = u << 16; return v.f;
}
__device__ inline float hif(unsigned u) {
  union { unsigned u; float f; } v; v.u = u & 0xffff0000u; return v.f;
}

// ---------------------------------------------------------------------------
// P1: pack w_qkv (first 128 rows) and w_m1 into MFMA A-frag order; zero gram2.
// A-frag (16x16x32): lane l holds A[m=l&15][k=(l>>4)*8+j], j=0..7.
__global__ void k_prep1(const float* __restrict__ wqkv, const float* __restrict__ wm1,
    short* __restrict__ apk, short* __restrict__ apm, float* __restrict__ gram2) {
  for (int idx = blockIdx.x * 256 + threadIdx.x; idx < 20480; idx += 16384) {
    if (idx < 8192) {
      const int j = idx & 7, lane = (idx >> 3) & 63, mt = (idx >> 9) & 7, cc = idx >> 12;
      const int o = mt * 16 + (lane & 15), c = cc * 32 + (lane >> 4) * 8 + j;
      apk[idx] = f2bf(wqkv[o * 64 + c]);
    } else if (idx < 12288) {
      const int k = idx - 8192;
      const int j = k & 7, lane = (k >> 3) & 63, mt = (k >> 9) & 3, cc = k >> 11;
      const int o = mt * 16 + (lane & 15), c = cc * 32 + (lane >> 4) * 8 + j;
      apm[k] = f2bf(wm1[o * 64 + c]);
    } else {
      gram2[idx - 12288] = 0.f;
    }
  }
}

// P2: pack w2 (OIHW 64x64x5x5) -> A-frag order [t][cc][mt][lane][j].
// Launched AFTER k_gram (its buffer aliases the dead qk region).
__global__ void k_prep2(const float* __restrict__ w2, short* __restrict__ apw2) {
  for (int idx = blockIdx.x * 256 + threadIdx.x; idx < 25 * 2 * 4 * 64 * 8; idx += 16384) {
    const int j = idx & 7, lane = (idx >> 3) & 63, mt = (idx >> 9) & 3,
              cc = (idx >> 11) & 1, t = idx >> 12;
    const int o = mt * 16 + (lane & 15);
    const int c = cc * 32 + (lane >> 4) * 8 + j;
    apw2[idx] = f2bf(w2[((size_t)o * 64 + c) * 25 + t]);
  }
}

// ---------------------------------------------------------------------------
// XT: x[b,c,n] fp32 -> x_t[b,n,64] bf16 (channel-innermost) via LDS transpose.
__global__ __launch_bounds__(256) void k_xt(const float* __restrict__ x,
    short* __restrict__ x_t) {
  __shared__ short lds[256 * 72];
  const int b = blockIdx.x >> 8, n0 = (blockIdx.x & 255) << 8;
  const int t = threadIdx.x;
#pragma unroll 4
  for (int c = 0; c < 64; ++c)
    lds[t * 72 + c] = f2bf(x[((size_t)(b * 64 + c)) * NN + n0 + t]);
  __syncthreads();
  short* dst = x_t + ((size_t)(b * NN + n0)) * 64;
#pragma unroll
  for (int it = 0; it < 8; ++it) {
    const int idx = it * 256 + t;
    const int nl = idx >> 3, cb = idx & 7;
    *(short8*)(dst + (size_t)nl * 64 + cb * 8) = *(const short8*)(lds + nl * 72 + cb * 8);
  }
}

// ---------------------------------------------------------------------------
// K1: qk 1x1 conv as MFMA GEMM: qk[b,o<128,n] = wqkv.x + b. B-frag straight
// from x_t (one short8 global load per k-chunk; no LDS).
__global__ __launch_bounds__(256, 4) void k_qk1x1(const short* __restrict__ x_t,
    const short* __restrict__ apk, const float* __restrict__ bias,
    short* __restrict__ qk) {
  const int b = blockIdx.x >> 10, ntile = blockIdx.x & 1023;
  const int wave = threadIdx.x >> 6, lane = threadIdx.x & 63;
  const int quad = lane >> 4, l15 = lane & 15;
  const int n = ntile * 64 + wave * 16 + l15;
  f32x4 acc[8];
#pragma unroll
  for (int mt = 0; mt < 8; ++mt) acc[mt] = (f32x4){0.f, 0.f, 0.f, 0.f};
#pragma unroll
  for (int cc = 0; cc < 2; ++cc) {
    const short8 bf = *(const short8*)(x_t + ((size_t)(b * NN + n)) * 64 + cc * 32 + quad * 8);
#pragma unroll
    for (int mt = 0; mt < 8; ++mt) {
      const short8 af = *(const short8*)(apk + ((cc * 8 + mt) * 64 + lane) * 8);
      acc[mt] = __builtin_amdgcn_mfma_f32_16x16x32_bf16(af, bf, acc[mt], 0, 0, 0);
    }
  }
#pragma unroll
  for (int mt = 0; mt < 8; ++mt)
#pragma unroll
    for (int reg = 0; reg < 4; ++reg) {
      const int o = mt * 16 + quad * 4 + reg;
      qk[((size_t)(b * 128 + o)) * NN + n] = f2bf(acc[mt][reg] + bias[o]);
    }
}

// ---------------------------------------------------------------------------
// K2: FUSED depthwise-3x3 + Gram, ILP-optimized.
// All 24 b128 mid-loads (3 dy-rows x 8 s-chunks) are hoisted into registers
// up front -> ONE global latency round-trip instead of 24 serial ones.
// Edge pixels (px0-1, px0+8) come from the hoisted data via __shfl.
__global__ __launch_bounds__(256, 3) void k_gram(const short* __restrict__ qk,
    const float* __restrict__ wdw, const float* __restrict__ bdw,
    float* __restrict__ gram2) {
  __shared__ float red[4][256];
  const int bh = blockIdx.x >> 6, chunk = blockIdx.x & 63;
  const int b = bh >> 3, h = bh & 7;
  const int wave = threadIdx.x >> 6, lane = threadIdx.x & 63;
  const int quad = lane >> 4, l15 = lane & 15;
  const int ch = (l15 < 8) ? (h * 8 + l15) : (64 + h * 8 + (l15 - 8));
  const short* plane = qk + ((size_t)(b * 128 + ch)) * NN;
  float wreg[9];
#pragma unroll
  for (int i = 0; i < 9; ++i) wreg[i] = wdw[ch * 9 + i];
  const float bias = bdw[ch];
  const int row = chunk * 4 + wave;          // wave-uniform output row 0..255
  const short* prow = plane + row * 256;
  // Hoisted row buffer: rb[dy][s] = 8 bf16 at px [32s+8q .. 32s+8q+7].
  u32x4 rb[3][8];
#pragma unroll
  for (int dy = 0; dy < 3; ++dy) {
    if (dy == 0 && row == 0) continue;       // wave-uniform
    if (dy == 2 && row == 255) continue;
    const short* pr = prow + (dy - 1) * 256 + quad * 8;
#pragma unroll
    for (int s = 0; s < 8; ++s)
      rb[dy][s] = *(const u32x4*)(pr + s * 32);
  }
  f32x4 acc = {0.f, 0.f, 0.f, 0.f};
#pragma unroll
  for (int s = 0; s < 8; ++s) {
    float a[8];
#pragma unroll
    for (int j = 0; j < 8; ++j) a[j] = bias;
#pragma unroll
    for (int dy = 0; dy < 3; ++dy) {
      if (dy == 0 && row == 0) continue;     // wave-uniform (shfls stay full-wave)
      if (dy == 2 && row == 255) continue;
      const unsigned w0_ = rb[dy][s][0], w1_ = rb[dy][s][1],
                     w2_ = rb[dy][s][2], w3_ = rb[dy][s][3];
      float m[10];
      m[1] = lof(w0_); m[2] = hif(w0_);
      m[3] = lof(w1_); m[4] = hif(w1_);
      m[5] = lof(w2_); m[6] = hif(w2_);
      m[7] = lof(w3_); m[8] = hif(w3_);
      const unsigned A3 = (unsigned)__shfl((int)w3_, (lane - 16) & 63, 64);
      const unsigned A0 = (unsigned)__shfl((int)w0_, (lane + 16) & 63, 64);
      float m0q0 = 0.f, m9q3 = 0.f;
      if (s > 0) {
        const unsigned B3 = (unsigned)__shfl((int)rb[dy][s - 1][3], (lane + 48) & 63, 64);
        m0q0 = hif(B3);
      }
      if (s < 7) {
        const unsigned B0 = (unsigned)__shfl((int)rb[dy][s + 1][0], (lane - 48) & 63, 64);
        m9q3 = lof(B0);
      }
      m[0] = (quad == 0) ? m0q0 : hif(A3);
      m[9] = (quad == 3) ? m9q3 : lof(A0);
      const float W0 = wreg[dy * 3], W1 = wreg[dy * 3 + 1], W2 = wreg[dy * 3 + 2];
#pragma unroll
      for (int j = 0; j < 8; ++j)
        a[j] = fmaf(W2, m[j + 2], fmaf(W1, m[j + 1], fmaf(W0, m[j], a[j])));
    }
    short8 frag;
#pragma unroll
    for (int j = 0; j < 8; ++j) frag[j] = f2bf(a[j]);
    acc = __builtin_amdgcn_mfma_f32_16x16x32_bf16(frag, frag, acc, 0, 0, 0);
  }
#pragma unroll
  for (int reg = 0; reg < 4; ++reg)
    red[wave][(quad * 4 + reg) * 16 + l15] = acc[reg];
  __syncthreads();
  {
    const int e = threadIdx.x;
    const float s4 = red[0][e] + red[1][e] + red[2][e] + red[3][e];
    atomicAdd(&gram2[bh * 256 + e], s4);
  }
}

// ---------------------------------------------------------------------------
// K3: m1 1x1 conv + BN as MFMA GEMM -> y_t[b,n,64] bf16 via LDS repack.
__global__ __launch_bounds__(256, 4) void k_m1_bn(const short* __restrict__ x_t,
    const short* __restrict__ apm, const float* __restrict__ gamma,
    const float* __restrict__ beta, const float* __restrict__ mean,
    const float* __restrict__ var, short* __restrict__ y_t) {
  __shared__ short lds[64 * 72];
  const int b = blockIdx.x >> 10, ntile = blockIdx.x & 1023;
  const int wave = threadIdx.x >> 6, lane = threadIdx.x & 63;
  const int quad = lane >> 4, l15 = lane & 15;
  const int n = ntile * 64 + wave * 16 + l15;
  f32x4 acc[4];
#pragma unroll
  for (int mt = 0; mt < 4; ++mt) acc[mt] = (f32x4){0.f, 0.f, 0.f, 0.f};
#pragma unroll
  for (int cc = 0; cc < 2; ++cc) {
    const short8 bf = *(const short8*)(x_t + ((size_t)(b * NN + n)) * 64 + cc * 32 + quad * 8);
#pragma unroll
    for (int mt = 0; mt < 4; ++mt) {
      const short8 af = *(const short8*)(apm + ((cc * 4 + mt) * 64 + lane) * 8);
      acc[mt] = __builtin_amdgcn_mfma_f32_16x16x32_bf16(af, bf, acc[mt], 0, 0, 0);
    }
  }
#pragma unroll
  for (int mt = 0; mt < 4; ++mt)
#pragma unroll
    for (int reg = 0; reg < 4; ++reg) {
      const int o = mt * 16 + quad * 4 + reg;
      const float sc = gamma[o] * rsqrtf(var[o] + 1e-5f);
      lds[(wave * 16 + l15) * 72 + o] = f2bf((acc[mt][reg] - mean[o]) * sc + beta[o]);
    }
  __syncthreads();
  short* dst = y_t + ((size_t)(b * NN + ntile * 64)) * 64;
#pragma unroll
  for (int it = 0; it < 2; ++it) {
    const int idx = it * 256 + threadIdx.x;
    const int lcol = idx >> 3, cb = idx & 7;
    *(short8*)(dst + (size_t)lcol * 64 + cb * 8) = *(const short8*)(lds + lcol * 72 + cb * 8);
  }
}

// ---------------------------------------------------------------------------
// K4: conv5x5 implicit-GEMM MFMA, 8-ROW TILE (8 rows x 64 cols per block,
// 512 blocks = exactly 2/CU). vs the 4-row tile: halves apw2 L2 traffic
// (A-frags amortized over 2x output), cuts halo staging 2.0x -> 1.5x,
// doubles MFMA per a-load. acc[4][2][4]=128 regs + ~50 live fits the
// (256,2) 256-reg budget -> no spill (WRITE_SIZE must stay 32MB).
// XOR-swizzled staging (conflict-free): L = rr*68+col (rr<12), cb 16B;
// byte = (L*64 + cb*16) ^ (((L>>1)&3)<<4).
__global__ __launch_bounds__(256, 2) void k_conv5(const short* __restrict__ y_t,
    const short* __restrict__ apw2, const short* __restrict__ x_t,
    short* __restrict__ v_t) {
  __shared__ short slds[8 * 64 * 76];  // 77,824 B >= staging 12*68*64B = 52,224 B
  char* sb = (char*)slds;
  const int b = blockIdx.x >> 7;
  const int rg = (blockIdx.x >> 2) & 31, cg = blockIdx.x & 3;
  const int r0 = rg * 8, x0 = cg * 64;
  const int wave = threadIdx.x >> 6, lane = threadIdx.x & 63;
  const int quad = lane >> 4, l15 = lane & 15;
  f32x4 acc[4][2][4];
#pragma unroll
  for (int mt = 0; mt < 4; ++mt)
#pragma unroll
    for (int r = 0; r < 2; ++r)
#pragma unroll
      for (int nt = 0; nt < 4; ++nt) acc[mt][r][nt] = (f32x4){0.f, 0.f, 0.f, 0.f};
  for (int cc = 0; cc < 2; ++cc) {
    if (cc) __syncthreads();
    for (int idx = threadIdx.x; idx < 12 * 68 * 4; idx += 256) {
      const int rr = idx / 272, rem = idx - rr * 272;
      const int col = rem >> 2, cb = rem & 3;
      const int gr = r0 - 2 + rr, gc = x0 - 2 + col;
      short8 val = {0, 0, 0, 0, 0, 0, 0, 0};
      if (gr >= 0 && gr < 256 && gc >= 0 && gc < 256)
        val = *(const short8*)(y_t + ((size_t)(b * NN + gr * 256 + gc)) * 64 + cc * 32 + cb * 8);
      const int L = rr * 68 + col;
      *(short8*)(sb + ((L * 64 + cb * 16) ^ (((L >> 1) & 3) << 4))) = val;
    }
    __syncthreads();
    for (int t = 0; t < 25; ++t) {
      const int dy = t / 5 - 2, dx = t % 5 - 2;
      short8 a[4];
#pragma unroll
      for (int mt = 0; mt < 4; ++mt)
        a[mt] = *(const short8*)(apw2 + (((t * 2 + cc) * 4 + mt) * 64 + lane) * 8);
#pragma unroll
      for (int r = 0; r < 2; ++r) {
        const int rr = wave * 2 + r + 2 + dy;
#pragma unroll
        for (int nt = 0; nt < 4; ++nt) {
          const int L = rr * 68 + nt * 16 + l15 + 2 + dx;
          const short8 bf =
              *(const short8*)(sb + ((L * 64 + quad * 16) ^ (((L >> 1) & 3) << 4)));
#pragma unroll
          for (int mt = 0; mt < 4; ++mt)
            acc[mt][r][nt] =
                __builtin_amdgcn_mfma_f32_16x16x32_bf16(a[mt], bf, acc[mt][r][nt], 0, 0, 0);
        }
      }
    }
  }
  __syncthreads();  // done reading staging; reuse slds as [row8][col64] stride 76
#pragma unroll
  for (int r = 0; r < 2; ++r) {
    const int lrow = wave * 2 + r;
    const int row = r0 + lrow;
#pragma unroll
    for (int nt = 0; nt < 4; ++nt) {
      const int lcol = nt * 16 + l15;
      const short* xp = x_t + ((size_t)(b * NN + row * 256 + x0 + lcol)) * 64 + quad * 4;
#pragma unroll
      for (int mt = 0; mt < 4; ++mt) {
        const short4b xv4 = *(const short4b*)(xp + mt * 16);
        short4b pk;
#pragma unroll
        for (int reg = 0; reg < 4; ++reg) {
          const float sg = 1.f / (1.f + __expf(-acc[mt][r][nt][reg]));
          pk[reg] = f2bf(bf2f(xv4[reg]) * (1.f + sg));
        }
        *(short4b*)(slds + (lrow * 64 + lcol) * 76 + mt * 16 + quad * 4) = pk;
      }
    }
  }
  __syncthreads();
#pragma unroll
  for (int it = 0; it < 16; ++it) {
    const int idx = it * 256 + threadIdx.x;
    const int cb = idx & 7, lcol = (idx >> 3) & 63, rr = idx >> 9;
    *(short8*)(v_t + ((size_t)(b * NN + (r0 + rr) * 256 + x0 + lcol)) * 64 + cb * 8) =
        *(const short8*)(slds + (rr * 64 + lcol) * 76 + cb * 8);
  }
}

// ---------------------------------------------------------------------------
// K5: softmax from gram2, fold wproj, emit E directly in bf16 A-frag order:
// Epack[b][cc][mt][lane][j] with A[m=o][k=cv].
__global__ __launch_bounds__(256) void k_attn_e(const float* __restrict__ gram2,
    const float* __restrict__ temp, const float* __restrict__ wproj,
    short* __restrict__ Epack) {
  __shared__ float attn[2048];
  const int t = threadIdx.x;
  {
    const int b = t >> 6, h = (t >> 3) & 7, c = t & 7;
    const float* g = gram2 + (b * 8 + h) * 256;
    const float qn = fmaxf(sqrtf(g[c * 16 + c]), 1e-12f);
    const float tp = temp[h];
    float row[8];
    float mx = -1e30f;
#pragma unroll
    for (int d = 0; d < 8; ++d) {
      const float kn = fmaxf(sqrtf(g[(8 + d) * 16 + (8 + d)]), 1e-12f);
      row[d] = g[c * 16 + 8 + d] / (qn * kn) * tp;
      mx = fmaxf(mx, row[d]);
    }
    float s = 0.f;
#pragma unroll
    for (int d = 0; d < 8; ++d) { row[d] = __expf(row[d] - mx); s += row[d]; }
    const float inv = 1.f / s;
#pragma unroll
    for (int d = 0; d < 8; ++d) attn[t * 8 + d] = row[d] * inv;
  }
  __syncthreads();
  for (int idx = t; idx < 16384; idx += 256) {
    const int j = idx & 7, lane = (idx >> 3) & 63, mt = (idx >> 9) & 3,
              cc = (idx >> 11) & 1, b = idx >> 12;
    const int o = mt * 16 + (lane & 15);
    const int cv = cc * 32 + (lane >> 4) * 8 + j;
    const int h = cv >> 3, d = cv & 7;
    float a = 0.f;
#pragma unroll
    for (int c2 = 0; c2 < 8; ++c2)
      a += wproj[o * 64 + h * 8 + c2] * attn[((b * 8 + h) * 8 + c2) * 8 + d];
    Epack[idx] = f2bf(a);
  }
}

// ---------------------------------------------------------------------------
// K6: out[b,o,n] = bproj[o] + E[b].v_t  as per-batch MFMA GEMM, fp32 stores.
__global__ __launch_bounds__(256, 4) void k_out(const short* __restrict__ v_t,
    const short* __restrict__ Epack, const float* __restrict__ bproj,
    float* __restrict__ out) {
  const int b = blockIdx.x >> 10, ntile = blockIdx.x & 1023;
  const int wave = threadIdx.x >> 6, lane = threadIdx.x & 63;
  const int quad = lane >> 4, l15 = lane & 15;
  const int n = ntile * 64 + wave * 16 + l15;
  f32x4 acc[4];
#pragma unroll
  for (int mt = 0; mt < 4; ++mt) acc[mt] = (f32x4){0.f, 0.f, 0.f, 0.f};
#pragma unroll
  for (int cc = 0; cc < 2; ++cc) {
    const short8 bf = *(const short8*)(v_t + ((size_t)(b * NN + n)) * 64 + cc * 32 + quad * 8);
#pragma unroll
    for (int mt = 0; mt < 4; ++mt) {
      const short8 af = *(const short8*)(Epack + (((b * 2 + cc) * 4 + mt) * 64 + lane) * 8);
      acc[mt] = __builtin_amdgcn_mfma_f32_16x16x32_bf16(af, bf, acc[mt], 0, 0, 0);
    }
  }
#pragma unroll
  for (int mt = 0; mt < 4; ++mt)
#pragma unroll
    for (int reg = 0; reg < 4; ++reg) {
      const int o = mt * 16 + quad * 4 + reg;
      out[((size_t)(b * 64 + o)) * NN + n] = acc[mt][reg] + bproj[o];
    }
}

// ---------------------------------------------------------------------------
// Workspace (byte offsets), total 134307840 <= proven ws capacity:
//  [0,   64M)  qk bf16 [b][128][N]  -> after k_gram: v_t [0,32M), apw2 @32M
//  [64M, 96M)  x_t bf16 [b][n][64]
//  [96M,128M)  y_t bf16 [b][n][64]
//  [128M, ..)  gram2 32KB | apk 16KB | apm 8KB | Epack 32KB
extern "C" void kernel_launch(void* const* d_in, const int* in_sizes, int n_in,
                              void* d_out, int out_size, void* d_ws, size_t ws_size,
                              hipStream_t stream) {
  const float* x     = (const float*)d_in[0];
  const float* wqkv  = (const float*)d_in[1];
  const float* bqkv  = (const float*)d_in[2];
  const float* wdw   = (const float*)d_in[3];
  const float* bdw   = (const float*)d_in[4];
  const float* wproj = (const float*)d_in[5];
  const float* bproj = (const float*)d_in[6];
  const float* temp  = (const float*)d_in[7];
  const float* wm1   = (const float*)d_in[8];
  const float* gamma = (const float*)d_in[9];
  const float* beta  = (const float*)d_in[10];
  const float* mean  = (const float*)d_in[11];
  const float* var   = (const float*)d_in[12];
  const float* wm2   = (const float*)d_in[13];

  char* wsb = (char*)d_ws;
  short* qk    = (short*)(wsb);
  short* v_t   = (short*)(wsb);                       // aliases qk (after k_gram)
  short* apw2  = (short*)(wsb + 33554432);            // aliases qk tail (after k_gram)
  short* x_t   = (short*)(wsb + 67108864);
  short* y_t   = (short*)(wsb + 100663296);
  float* gram2 = (float*)(wsb + 134217728);
  short* apk   = (short*)(wsb + 134217728 + 32768);
  short* apm   = (short*)(wsb + 134217728 + 49152);
  short* Epack = (short*)(wsb + 134217728 + 57344);
  float* out   = (float*)d_out;

  k_prep1<<<dim3(64), dim3(256), 0, stream>>>(wqkv, wm1, apk, apm, gram2);
  k_xt<<<dim3(1024), dim3(256), 0, stream>>>(x, x_t);
  k_qk1x1<<<dim3(4096), dim3(256), 0, stream>>>(x_t, apk, bqkv, qk);
  k_gram<<<dim3(2048), dim3(256), 0, stream>>>(qk, wdw, bdw, gram2);
  k_prep2<<<dim3(64), dim3(256), 0, stream>>>(wm2, apw2);
  k_m1_bn<<<dim3(4096), dim3(256), 0, stream>>>(x_t, apm, gamma, beta, mean, var, y_t);
  k_conv5<<<dim3(512), dim3(256), 0, stream>>>(y_t, apw2, x_t, v_t);
  k_attn_e<<<dim3(1), dim3(256), 0, stream>>>(gram2, temp, wproj, Epack);
  k_out<<<dim3(4096), dim3(256), 0, stream>>>(v_t, Epack, bproj, out);
}

// Round 7
// 298.955 us; speedup vs baseline: 1.3231x; 1.0203x over previous
//
#include <hip/hip_runtime.h>
#include <math.h>

#define B 4
#define C 64
#define NN 65536

typedef __attribute__((ext_vector_type(8))) short short8;
typedef __attribute__((ext_vector_type(4))) short short4b;
typedef __attribute__((ext_vector_type(4))) float f32x4;
typedef __attribute__((ext_vector_type(4))) unsigned int u32x4;

__device__ inline float bf2f(short s) {
  union { unsigned u; float f; } v; v.u = ((unsigned)(unsigned short)s) << 16; return v.f;
}
__device__ inline short f2bf(float f) {
  union { float f; unsigned u; } v; v.f = f;
  unsigned r = v.u + 0x7FFFu + ((v.u >> 16) & 1u);  // RNE
  return (short)(r >> 16);
}
// bf16 pair unpack: low half / high half of a 32-bit word.
__device__ inline float lof(unsigned u) {
  union { unsigned u; float f; } v; v.u = u << 16; return v.f;
}
__device__ inline float hif(unsigned u) {
  union { unsigned u; float f; } v; v.u = u & 0xffff0000u; return v.f;
}

// ---------------------------------------------------------------------------
// XT (+prep1 tail): x[b,c,n] fp32 -> x_t[b,n,64] bf16 via LDS transpose.
// LDS stride 66 (not 72): b16 write bank = (33t)%32 = t%32 -> 2-way (free);
// stride 72 was 8-way. Tail blocks (>=1024) pack w_qkv/w_m1 + zero gram2.
__global__ __launch_bounds__(256) void k_xt(const float* __restrict__ x,
    short* __restrict__ x_t, const float* __restrict__ wqkv,
    const float* __restrict__ wm1, short* __restrict__ apk,
    short* __restrict__ apm, float* __restrict__ gram2) {
  if (blockIdx.x >= 1024) {  // folded k_prep1
    const int bid = blockIdx.x - 1024;
    for (int idx = bid * 256 + threadIdx.x; idx < 20480; idx += 16384) {
      if (idx < 8192) {
        const int j = idx & 7, lane = (idx >> 3) & 63, mt = (idx >> 9) & 7, cc = idx >> 12;
        const int o = mt * 16 + (lane & 15), c = cc * 32 + (lane >> 4) * 8 + j;
        apk[idx] = f2bf(wqkv[o * 64 + c]);
      } else if (idx < 12288) {
        const int k = idx - 8192;
        const int j = k & 7, lane = (k >> 3) & 63, mt = (k >> 9) & 3, cc = k >> 11;
        const int o = mt * 16 + (lane & 15), c = cc * 32 + (lane >> 4) * 8 + j;
        apm[k] = f2bf(wm1[o * 64 + c]);
      } else {
        gram2[idx - 12288] = 0.f;
      }
    }
    return;
  }
  __shared__ short lds[256 * 66];
  const int b = blockIdx.x >> 8, n0 = (blockIdx.x & 255) << 8;
  const int t = threadIdx.x;
#pragma unroll 4
  for (int c = 0; c < 64; ++c)
    lds[t * 66 + c] = f2bf(x[((size_t)(b * 64 + c)) * NN + n0 + t]);
  __syncthreads();
  short* dst = x_t + ((size_t)(b * NN + n0)) * 64;
#pragma unroll
  for (int it = 0; it < 8; ++it) {
    const int idx = it * 256 + t;
    const int nl = idx >> 3, cb = idx & 7;
    *(short8*)(dst + (size_t)nl * 64 + cb * 8) = *(const short8*)(lds + nl * 66 + cb * 8);
  }
}

// ---------------------------------------------------------------------------
// K1: qk 1x1 conv as MFMA GEMM: qk[b,o<128,n] = wqkv.x + b.
__global__ __launch_bounds__(256, 4) void k_qk1x1(const short* __restrict__ x_t,
    const short* __restrict__ apk, const float* __restrict__ bias,
    short* __restrict__ qk) {
  const int b = blockIdx.x >> 10, ntile = blockIdx.x & 1023;
  const int wave = threadIdx.x >> 6, lane = threadIdx.x & 63;
  const int quad = lane >> 4, l15 = lane & 15;
  const int n = ntile * 64 + wave * 16 + l15;
  f32x4 acc[8];
#pragma unroll
  for (int mt = 0; mt < 8; ++mt) acc[mt] = (f32x4){0.f, 0.f, 0.f, 0.f};
#pragma unroll
  for (int cc = 0; cc < 2; ++cc) {
    const short8 bf = *(const short8*)(x_t + ((size_t)(b * NN + n)) * 64 + cc * 32 + quad * 8);
#pragma unroll
    for (int mt = 0; mt < 8; ++mt) {
      const short8 af = *(const short8*)(apk + ((cc * 8 + mt) * 64 + lane) * 8);
      acc[mt] = __builtin_amdgcn_mfma_f32_16x16x32_bf16(af, bf, acc[mt], 0, 0, 0);
    }
  }
#pragma unroll
  for (int mt = 0; mt < 8; ++mt)
#pragma unroll
    for (int reg = 0; reg < 4; ++reg) {
      const int o = mt * 16 + quad * 4 + reg;
      qk[((size_t)(b * 128 + o)) * NN + n] = f2bf(acc[mt][reg] + bias[o]);
    }
}

// ---------------------------------------------------------------------------
// K2: FUSED depthwise-3x3 + Gram, ILP-optimized (register-hoisted rows,
// shfl edges). Unchanged from round 5.
__global__ __launch_bounds__(256, 3) void k_gram(const short* __restrict__ qk,
    const float* __restrict__ wdw, const float* __restrict__ bdw,
    float* __restrict__ gram2) {
  __shared__ float red[4][256];
  const int bh = blockIdx.x >> 6, chunk = blockIdx.x & 63;
  const int b = bh >> 3, h = bh & 7;
  const int wave = threadIdx.x >> 6, lane = threadIdx.x & 63;
  const int quad = lane >> 4, l15 = lane & 15;
  const int ch = (l15 < 8) ? (h * 8 + l15) : (64 + h * 8 + (l15 - 8));
  const short* plane = qk + ((size_t)(b * 128 + ch)) * NN;
  float wreg[9];
#pragma unroll
  for (int i = 0; i < 9; ++i) wreg[i] = wdw[ch * 9 + i];
  const float bias = bdw[ch];
  const int row = chunk * 4 + wave;          // wave-uniform output row 0..255
  const short* prow = plane + row * 256;
  u32x4 rb[3][8];
#pragma unroll
  for (int dy = 0; dy < 3; ++dy) {
    if (dy == 0 && row == 0) continue;       // wave-uniform
    if (dy == 2 && row == 255) continue;
    const short* pr = prow + (dy - 1) * 256 + quad * 8;
#pragma unroll
    for (int s = 0; s < 8; ++s)
      rb[dy][s] = *(const u32x4*)(pr + s * 32);
  }
  f32x4 acc = {0.f, 0.f, 0.f, 0.f};
#pragma unroll
  for (int s = 0; s < 8; ++s) {
    float a[8];
#pragma unroll
    for (int j = 0; j < 8; ++j) a[j] = bias;
#pragma unroll
    for (int dy = 0; dy < 3; ++dy) {
      if (dy == 0 && row == 0) continue;
      if (dy == 2 && row == 255) continue;
      const unsigned w0_ = rb[dy][s][0], w1_ = rb[dy][s][1],
                     w2_ = rb[dy][s][2], w3_ = rb[dy][s][3];
      float m[10];
      m[1] = lof(w0_); m[2] = hif(w0_);
      m[3] = lof(w1_); m[4] = hif(w1_);
      m[5] = lof(w2_); m[6] = hif(w2_);
      m[7] = lof(w3_); m[8] = hif(w3_);
      const unsigned A3 = (unsigned)__shfl((int)w3_, (lane - 16) & 63, 64);
      const unsigned A0 = (unsigned)__shfl((int)w0_, (lane + 16) & 63, 64);
      float m0q0 = 0.f, m9q3 = 0.f;
      if (s > 0) {
        const unsigned B3 = (unsigned)__shfl((int)rb[dy][s - 1][3], (lane + 48) & 63, 64);
        m0q0 = hif(B3);
      }
      if (s < 7) {
        const unsigned B0 = (unsigned)__shfl((int)rb[dy][s + 1][0], (lane - 48) & 63, 64);
        m9q3 = lof(B0);
      }
      m[0] = (quad == 0) ? m0q0 : hif(A3);
      m[9] = (quad == 3) ? m9q3 : lof(A0);
      const float W0 = wreg[dy * 3], W1 = wreg[dy * 3 + 1], W2 = wreg[dy * 3 + 2];
#pragma unroll
      for (int j = 0; j < 8; ++j)
        a[j] = fmaf(W2, m[j + 2], fmaf(W1, m[j + 1], fmaf(W0, m[j], a[j])));
    }
    short8 frag;
#pragma unroll
    for (int j = 0; j < 8; ++j) frag[j] = f2bf(a[j]);
    acc = __builtin_amdgcn_mfma_f32_16x16x32_bf16(frag, frag, acc, 0, 0, 0);
  }
#pragma unroll
  for (int reg = 0; reg < 4; ++reg)
    red[wave][(quad * 4 + reg) * 16 + l15] = acc[reg];
  __syncthreads();
  {
    const int e = threadIdx.x;
    const float s4 = red[0][e] + red[1][e] + red[2][e] + red[3][e];
    atomicAdd(&gram2[bh * 256 + e], s4);
  }
}

// ---------------------------------------------------------------------------
// K3 (+prep2 tail): m1 1x1 conv + BN -> y_t[b,n,64] bf16. LDS stride 66
// (2-way write banks vs 8-way at 72). Tail blocks (>=4096) pack w2 -> apw2
// (safe here: after k_gram, before k_conv5).
__global__ __launch_bounds__(256, 4) void k_m1_bn(const short* __restrict__ x_t,
    const short* __restrict__ apm, const float* __restrict__ gamma,
    const float* __restrict__ beta, const float* __restrict__ mean,
    const float* __restrict__ var, short* __restrict__ y_t,
    const float* __restrict__ w2, short* __restrict__ apw2) {
  if (blockIdx.x >= 4096) {  // folded k_prep2
    const int bid = blockIdx.x - 4096;
    for (int idx = bid * 256 + threadIdx.x; idx < 25 * 2 * 4 * 64 * 8; idx += 16384) {
      const int j = idx & 7, lane = (idx >> 3) & 63, mt = (idx >> 9) & 3,
                cc = (idx >> 11) & 1, t = idx >> 12;
      const int o = mt * 16 + (lane & 15);
      const int c = cc * 32 + (lane >> 4) * 8 + j;
      apw2[idx] = f2bf(w2[((size_t)o * 64 + c) * 25 + t]);
    }
    return;
  }
  __shared__ short lds[64 * 66];
  const int b = blockIdx.x >> 10, ntile = blockIdx.x & 1023;
  const int wave = threadIdx.x >> 6, lane = threadIdx.x & 63;
  const int quad = lane >> 4, l15 = lane & 15;
  const int n = ntile * 64 + wave * 16 + l15;
  f32x4 acc[4];
#pragma unroll
  for (int mt = 0; mt < 4; ++mt) acc[mt] = (f32x4){0.f, 0.f, 0.f, 0.f};
#pragma unroll
  for (int cc = 0; cc < 2; ++cc) {
    const short8 bf = *(const short8*)(x_t + ((size_t)(b * NN + n)) * 64 + cc * 32 + quad * 8);
#pragma unroll
    for (int mt = 0; mt < 4; ++mt) {
      const short8 af = *(const short8*)(apm + ((cc * 4 + mt) * 64 + lane) * 8);
      acc[mt] = __builtin_amdgcn_mfma_f32_16x16x32_bf16(af, bf, acc[mt], 0, 0, 0);
    }
  }
#pragma unroll
  for (int mt = 0; mt < 4; ++mt)
#pragma unroll
    for (int reg = 0; reg < 4; ++reg) {
      const int o = mt * 16 + quad * 4 + reg;
      const float sc = gamma[o] * rsqrtf(var[o] + 1e-5f);
      lds[(wave * 16 + l15) * 66 + o] = f2bf((acc[mt][reg] - mean[o]) * sc + beta[o]);
    }
  __syncthreads();
  short* dst = y_t + ((size_t)(b * NN + ntile * 64)) * 64;
#pragma unroll
  for (int it = 0; it < 2; ++it) {
    const int idx = it * 256 + threadIdx.x;
    const int lcol = idx >> 3, cb = idx & 7;
    *(short8*)(dst + (size_t)lcol * 64 + cb * 8) = *(const short8*)(lds + lcol * 66 + cb * 8);
  }
}

// ---------------------------------------------------------------------------
// K4: conv5x5 implicit-GEMM MFMA, SINGLE-PHASE staging: all 64 channels of
// the 8x68 halo staged once (69.6 KB), then 25 taps of uninterrupted compute
// (one barrier, not three; no mid-loop vmcnt drain). Each nt issues an
// INDEPENDENT cc0/cc1 read pair (2x LDS-read ILP, shared L addr math).
// Swizzle: row L = rr*68+col holds 128 B (64 ch); byte =
// L*128 + ((cb*16) ^ ((L&7)<<4)). Write: 8 lanes per 4-bank group (ideal).
// Read (fixed cc): bank group 4*((4cc+quad)^(L&7)) -> 8 lanes/group (ideal).
// Fields disjoint (L*128 bits>=7, cb*16 and key bits 4-6) -> bijective.
__global__ __launch_bounds__(256, 2) void k_conv5(const short* __restrict__ y_t,
    const short* __restrict__ apw2, const short* __restrict__ x_t,
    short* __restrict__ v_t) {
  __shared__ short slds[8 * 68 * 64];  // 69,632 B
  char* sb = (char*)slds;
  const int b = blockIdx.x >> 8;
  const int rg = (blockIdx.x >> 2) & 63, cg = blockIdx.x & 3;
  const int r0 = rg * 4, x0 = cg * 64;
  const int wave = threadIdx.x >> 6, lane = threadIdx.x & 63;
  const int quad = lane >> 4, l15 = lane & 15;
  f32x4 acc[4][4];
#pragma unroll
  for (int mt = 0; mt < 4; ++mt)
#pragma unroll
    for (int nt = 0; nt < 4; ++nt) acc[mt][nt] = (f32x4){0.f, 0.f, 0.f, 0.f};
  // Stage all 64 ch of the 8x68 halo: 4352 b128 = 17 iters/thread.
  for (int idx = threadIdx.x; idx < 8 * 68 * 8; idx += 256) {
    const int rr = idx / 544, rem = idx - rr * 544;
    const int col = rem >> 3, cb = rem & 7;
    const int gr = r0 - 2 + rr, gc = x0 - 2 + col;
    short8 val = {0, 0, 0, 0, 0, 0, 0, 0};
    if (gr >= 0 && gr < 256 && gc >= 0 && gc < 256)
      val = *(const short8*)(y_t + ((size_t)(b * NN + gr * 256 + gc)) * 64 + cb * 8);
    const int L = rr * 68 + col;
    *(short8*)(sb + L * 128 + ((cb * 16) ^ ((L & 7) << 4))) = val;
  }
  __syncthreads();
  for (int t = 0; t < 25; ++t) {
    const int dy = t / 5 - 2, dx = t % 5 - 2;
    short8 a0[4], a1[4];
#pragma unroll
    for (int mt = 0; mt < 4; ++mt) {
      a0[mt] = *(const short8*)(apw2 + (((t * 2 + 0) * 4 + mt) * 64 + lane) * 8);
      a1[mt] = *(const short8*)(apw2 + (((t * 2 + 1) * 4 + mt) * 64 + lane) * 8);
    }
    const int rr = wave + 2 + dy;
#pragma unroll
    for (int nt = 0; nt < 4; ++nt) {
      const int L = rr * 68 + nt * 16 + l15 + 2 + dx;
      const int off0 = L * 128 + ((quad * 16) ^ ((L & 7) << 4));
      const short8 bf0 = *(const short8*)(sb + off0);
      const short8 bf1 = *(const short8*)(sb + (off0 ^ 64));
#pragma unroll
      for (int mt = 0; mt < 4; ++mt) {
        acc[mt][nt] = __builtin_amdgcn_mfma_f32_16x16x32_bf16(a0[mt], bf0, acc[mt][nt], 0, 0, 0);
        acc[mt][nt] = __builtin_amdgcn_mfma_f32_16x16x32_bf16(a1[mt], bf1, acc[mt][nt], 0, 0, 0);
      }
    }
  }
  __syncthreads();  // done reading staging; reuse slds as [row4][col64] stride 76
  const int row = r0 + wave;
#pragma unroll
  for (int nt = 0; nt < 4; ++nt) {
    const int lcol = nt * 16 + l15;
    const short* xp = x_t + ((size_t)(b * NN + row * 256 + x0 + lcol)) * 64 + quad * 4;
#pragma unroll
    for (int mt = 0; mt < 4; ++mt) {
      const short4b xv4 = *(const short4b*)(xp + mt * 16);
      short4b pk;
#pragma unroll
      for (int reg = 0; reg < 4; ++reg) {
        const float sg = 1.f / (1.f + __expf(-acc[mt][nt][reg]));
        pk[reg] = f2bf(bf2f(xv4[reg]) * (1.f + sg));
      }
      *(short4b*)(slds + (wave * 64 + lcol) * 76 + mt * 16 + quad * 4) = pk;
    }
  }
  __syncthreads();
#pragma unroll
  for (int it = 0; it < 8; ++it) {
    const int idx = it * 256 + threadIdx.x;
    const int cb = idx & 7, lcol = (idx >> 3) & 63, rr = idx >> 9;
    *(short8*)(v_t + ((size_t)(b * NN + (r0 + rr) * 256 + x0 + lcol)) * 64 + cb * 8) =
        *(const short8*)(slds + (rr * 64 + lcol) * 76 + cb * 8);
  }
}

// ---------------------------------------------------------------------------
// K5: softmax from gram2, fold wproj, emit E in bf16 A-frag order.
// Grid 16 (was 1): every block redundantly computes the tiny softmax, then
// handles 1024 of the 16384 Epack elements.
__global__ __launch_bounds__(256) void k_attn_e(const float* __restrict__ gram2,
    const float* __restrict__ temp, const float* __restrict__ wproj,
    short* __restrict__ Epack) {
  __shared__ float attn[2048];
  const int t = threadIdx.x;
  {
    const int b = t >> 6, h = (t >> 3) & 7, c = t & 7;
    const float* g = gram2 + (b * 8 + h) * 256;
    const float qn = fmaxf(sqrtf(g[c * 16 + c]), 1e-12f);
    const float tp = temp[h];
    float row[8];
    float mx = -1e30f;
#pragma unroll
    for (int d = 0; d < 8; ++d) {
      const float kn = fmaxf(sqrtf(g[(8 + d) * 16 + (8 + d)]), 1e-12f);
      row[d] = g[c * 16 + 8 + d] / (qn * kn) * tp;
      mx = fmaxf(mx, row[d]);
    }
    float s = 0.f;
#pragma unroll
    for (int d = 0; d < 8; ++d) { row[d] = __expf(row[d] - mx); s += row[d]; }
    const float inv = 1.f / s;
#pragma unroll
    for (int d = 0; d < 8; ++d) attn[t * 8 + d] = row[d] * inv;
  }
  __syncthreads();
  for (int idx = blockIdx.x * 1024 + t; idx < (blockIdx.x + 1) * 1024; idx += 256) {
    const int j = idx & 7, lane = (idx >> 3) & 63, mt = (idx >> 9) & 3,
              cc = (idx >> 11) & 1, b = idx >> 12;
    const int o = mt * 16 + (lane & 15);
    const int cv = cc * 32 + (lane >> 4) * 8 + j;
    const int h = cv >> 3, d = cv & 7;
    float a = 0.f;
#pragma unroll
    for (int c2 = 0; c2 < 8; ++c2)
      a += wproj[o * 64 + h * 8 + c2] * attn[((b * 8 + h) * 8 + c2) * 8 + d];
    Epack[idx] = f2bf(a);
  }
}

// ---------------------------------------------------------------------------
// K6: out[b,o,n] = bproj[o] + E[b].v_t  as per-batch MFMA GEMM, fp32 stores.
__global__ __launch_bounds__(256, 4) void k_out(const short* __restrict__ v_t,
    const short* __restrict__ Epack, const float* __restrict__ bproj,
    float* __restrict__ out) {
  const int b = blockIdx.x >> 10, ntile = blockIdx.x & 1023;
  const int wave = threadIdx.x >> 6, lane = threadIdx.x & 63;
  const int quad = lane >> 4, l15 = lane & 15;
  const int n = ntile * 64 + wave * 16 + l15;
  f32x4 acc[4];
#pragma unroll
  for (int mt = 0; mt < 4; ++mt) acc[mt] = (f32x4){0.f, 0.f, 0.f, 0.f};
#pragma unroll
  for (int cc = 0; cc < 2; ++cc) {
    const short8 bf = *(const short8*)(v_t + ((size_t)(b * NN + n)) * 64 + cc * 32 + quad * 8);
#pragma unroll
    for (int mt = 0; mt < 4; ++mt) {
      const short8 af = *(const short8*)(Epack + (((b * 2 + cc) * 4 + mt) * 64 + lane) * 8);
      acc[mt] = __builtin_amdgcn_mfma_f32_16x16x32_bf16(af, bf, acc[mt], 0, 0, 0);
    }
  }
#pragma unroll
  for (int mt = 0; mt < 4; ++mt)
#pragma unroll
    for (int reg = 0; reg < 4; ++reg) {
      const int o = mt * 16 + quad * 4 + reg;
      out[((size_t)(b * 64 + o)) * NN + n] = acc[mt][reg] + bproj[o];
    }
}

// ---------------------------------------------------------------------------
// Workspace (byte offsets), total 134307840 <= proven ws capacity:
//  [0,   64M)  qk bf16 [b][128][N]  -> after k_gram: v_t [0,32M), apw2 @32M
//  [64M, 96M)  x_t bf16 [b][n][64]
//  [96M,128M)  y_t bf16 [b][n][64]
//  [128M, ..)  gram2 32KB | apk 16KB | apm 8KB | Epack 32KB
extern "C" void kernel_launch(void* const* d_in, const int* in_sizes, int n_in,
                              void* d_out, int out_size, void* d_ws, size_t ws_size,
                              hipStream_t stream) {
  const float* x     = (const float*)d_in[0];
  const float* wqkv  = (const float*)d_in[1];
  const float* bqkv  = (const float*)d_in[2];
  const float* wdw   = (const float*)d_in[3];
  const float* bdw   = (const float*)d_in[4];
  const float* wproj = (const float*)d_in[5];
  const float* bproj = (const float*)d_in[6];
  const float* temp  = (const float*)d_in[7];
  const float* wm1   = (const float*)d_in[8];
  const float* gamma = (const float*)d_in[9];
  const float* beta  = (const float*)d_in[10];
  const float* mean  = (const float*)d_in[11];
  const float* var   = (const float*)d_in[12];
  const float* wm2   = (const float*)d_in[13];

  char* wsb = (char*)d_ws;
  short* qk    = (short*)(wsb);
  short* v_t   = (short*)(wsb);                       // aliases qk (after k_gram)
  short* apw2  = (short*)(wsb + 33554432);            // aliases qk tail (after k_gram)
  short* x_t   = (short*)(wsb + 67108864);
  short* y_t   = (short*)(wsb + 100663296);
  float* gram2 = (float*)(wsb + 134217728);
  short* apk   = (short*)(wsb + 134217728 + 32768);
  short* apm   = (short*)(wsb + 134217728 + 49152);
  short* Epack = (short*)(wsb + 134217728 + 57344);
  float* out   = (float*)d_out;

  k_xt<<<dim3(1088), dim3(256), 0, stream>>>(x, x_t, wqkv, wm1, apk, apm, gram2);
  k_qk1x1<<<dim3(4096), dim3(256), 0, stream>>>(x_t, apk, bqkv, qk);
  k_gram<<<dim3(2048), dim3(256), 0, stream>>>(qk, wdw, bdw, gram2);
  k_m1_bn<<<dim3(4160), dim3(256), 0, stream>>>(x_t, apm, gamma, beta, mean, var, y_t,
                                                wm2, apw2);
  k_conv5<<<dim3(1024), dim3(256), 0, stream>>>(y_t, apw2, x_t, v_t);
  k_attn_e<<<dim3(16), dim3(256), 0, stream>>>(gram2, temp, wproj, Epack);
  k_out<<<dim3(4096), dim3(256), 0, stream>>>(v_t, Epack, bproj, out);
}

// Round 8
// 293.491 us; speedup vs baseline: 1.3477x; 1.0186x over previous
//
#include <hip/hip_runtime.h>
#include <math.h>

#define B 4
#define C 64
#define NN 65536

typedef __attribute__((ext_vector_type(8))) short short8;
typedef __attribute__((ext_vector_type(4))) short short4b;
typedef __attribute__((ext_vector_type(4))) float f32x4;
typedef __attribute__((ext_vector_type(4))) unsigned int u32x4;

__device__ inline float bf2f(short s) {
  union { unsigned u; float f; } v; v.u = ((unsigned)(unsigned short)s) << 16; return v.f;
}
__device__ inline short f2bf(float f) {
  union { float f; unsigned u; } v; v.f = f;
  unsigned r = v.u + 0x7FFFu + ((v.u >> 16) & 1u);  // RNE
  return (short)(r >> 16);
}
// bf16 pair unpack: low half / high half of a 32-bit word.
__device__ inline float lof(unsigned u) {
  union { unsigned u; float f; } v; v.u = u << 16; return v.f;
}
__device__ inline float hif(unsigned u) {
  union { unsigned u; float f; } v; v.u = u & 0xffff0000u; return v.f;
}

// ---------------------------------------------------------------------------
// XT (+prep1 tail): x[b,c,n] fp32 -> x_t[b,n,64] bf16 via LDS transpose.
// LDS stride 66: b16 write bank = t%32 -> 2-way (free). Tail packs weights.
__global__ __launch_bounds__(256) void k_xt(const float* __restrict__ x,
    short* __restrict__ x_t, const float* __restrict__ wqkv,
    const float* __restrict__ wm1, short* __restrict__ apk,
    short* __restrict__ apm, float* __restrict__ gram2) {
  if (blockIdx.x >= 1024) {  // folded k_prep1
    const int bid = blockIdx.x - 1024;
    for (int idx = bid * 256 + threadIdx.x; idx < 20480; idx += 16384) {
      if (idx < 8192) {
        const int j = idx & 7, lane = (idx >> 3) & 63, mt = (idx >> 9) & 7, cc = idx >> 12;
        const int o = mt * 16 + (lane & 15), c = cc * 32 + (lane >> 4) * 8 + j;
        apk[idx] = f2bf(wqkv[o * 64 + c]);
      } else if (idx < 12288) {
        const int k = idx - 8192;
        const int j = k & 7, lane = (k >> 3) & 63, mt = (k >> 9) & 3, cc = k >> 11;
        const int o = mt * 16 + (lane & 15), c = cc * 32 + (lane >> 4) * 8 + j;
        apm[k] = f2bf(wm1[o * 64 + c]);
      } else {
        gram2[idx - 12288] = 0.f;
      }
    }
    return;
  }
  __shared__ short lds[256 * 66];
  const int b = blockIdx.x >> 8, n0 = (blockIdx.x & 255) << 8;
  const int t = threadIdx.x;
#pragma unroll 4
  for (int c = 0; c < 64; ++c)
    lds[t * 66 + c] = f2bf(x[((size_t)(b * 64 + c)) * NN + n0 + t]);
  __syncthreads();
  short* dst = x_t + ((size_t)(b * NN + n0)) * 64;
#pragma unroll
  for (int it = 0; it < 8; ++it) {
    const int idx = it * 256 + t;
    const int nl = idx >> 3, cb = idx & 7;
    *(short8*)(dst + (size_t)nl * 64 + cb * 8) = *(const short8*)(lds + nl * 66 + cb * 8);
  }
}

// ---------------------------------------------------------------------------
// K1: qk 1x1 conv as MFMA GEMM: qk[b,o<128,n] = wqkv.x + b.
__global__ __launch_bounds__(256, 4) void k_qk1x1(const short* __restrict__ x_t,
    const short* __restrict__ apk, const float* __restrict__ bias,
    short* __restrict__ qk) {
  const int b = blockIdx.x >> 10, ntile = blockIdx.x & 1023;
  const int wave = threadIdx.x >> 6, lane = threadIdx.x & 63;
  const int quad = lane >> 4, l15 = lane & 15;
  const int n = ntile * 64 + wave * 16 + l15;
  f32x4 acc[8];
#pragma unroll
  for (int mt = 0; mt < 8; ++mt) acc[mt] = (f32x4){0.f, 0.f, 0.f, 0.f};
#pragma unroll
  for (int cc = 0; cc < 2; ++cc) {
    const short8 bf = *(const short8*)(x_t + ((size_t)(b * NN + n)) * 64 + cc * 32 + quad * 8);
#pragma unroll
    for (int mt = 0; mt < 8; ++mt) {
      const short8 af = *(const short8*)(apk + ((cc * 8 + mt) * 64 + lane) * 8);
      acc[mt] = __builtin_amdgcn_mfma_f32_16x16x32_bf16(af, bf, acc[mt], 0, 0, 0);
    }
  }
#pragma unroll
  for (int mt = 0; mt < 8; ++mt)
#pragma unroll
    for (int reg = 0; reg < 4; ++reg) {
      const int o = mt * 16 + quad * 4 + reg;
      qk[((size_t)(b * 128 + o)) * NN + n] = f2bf(acc[mt][reg] + bias[o]);
    }
}

// ---------------------------------------------------------------------------
// K2: FUSED depthwise-3x3 + Gram, register-hoisted rows.
// Edge pixels via SINGLE shfl each (source-side select): for m[0] both the
// intra-chunk (quad>0 <- w3 of quad-1 at lane-16) and wrap (quad==0 <-
// rb[s-1][3] of quad 3 at lane+48 == lane-16 mod 64) routes share srclane
// (lane-16)&63, so src lane selects (quad==3 ? rb[s-1][3] : w3) and one
// ds_bpermute serves both. Halves the shfl/LDS-pipe traffic vs round 5.
__global__ __launch_bounds__(256, 3) void k_gram(const short* __restrict__ qk,
    const float* __restrict__ wdw, const float* __restrict__ bdw,
    float* __restrict__ gram2) {
  __shared__ float red[4][256];
  const int bh = blockIdx.x >> 6, chunk = blockIdx.x & 63;
  const int b = bh >> 3, h = bh & 7;
  const int wave = threadIdx.x >> 6, lane = threadIdx.x & 63;
  const int quad = lane >> 4, l15 = lane & 15;
  const int ch = (l15 < 8) ? (h * 8 + l15) : (64 + h * 8 + (l15 - 8));
  const short* plane = qk + ((size_t)(b * 128 + ch)) * NN;
  float wreg[9];
#pragma unroll
  for (int i = 0; i < 9; ++i) wreg[i] = wdw[ch * 9 + i];
  const float bias = bdw[ch];
  const int row = chunk * 4 + wave;          // wave-uniform output row 0..255
  const short* prow = plane + row * 256;
  u32x4 rb[3][8];
#pragma unroll
  for (int dy = 0; dy < 3; ++dy) {
    if (dy == 0 && row == 0) continue;       // wave-uniform
    if (dy == 2 && row == 255) continue;
    const short* pr = prow + (dy - 1) * 256 + quad * 8;
#pragma unroll
    for (int s = 0; s < 8; ++s)
      rb[dy][s] = *(const u32x4*)(pr + s * 32);
  }
  f32x4 acc = {0.f, 0.f, 0.f, 0.f};
#pragma unroll
  for (int s = 0; s < 8; ++s) {
    float a[8];
#pragma unroll
    for (int j = 0; j < 8; ++j) a[j] = bias;
#pragma unroll
    for (int dy = 0; dy < 3; ++dy) {
      if (dy == 0 && row == 0) continue;     // wave-uniform (shfls stay full-wave)
      if (dy == 2 && row == 255) continue;
      const unsigned w0_ = rb[dy][s][0], w1_ = rb[dy][s][1],
                     w2_ = rb[dy][s][2], w3_ = rb[dy][s][3];
      float m[10];
      m[1] = lof(w0_); m[2] = hif(w0_);
      m[3] = lof(w1_); m[4] = hif(w1_);
      m[5] = lof(w2_); m[6] = hif(w2_);
      m[7] = lof(w3_); m[8] = hif(w3_);
      unsigned m0w, m9w;
      if (s == 0) {
        m0w = (unsigned)__shfl((int)w3_, (lane - 16) & 63, 64);
      } else {
        const unsigned w3sel = (quad == 3) ? rb[dy][s - 1][3] : w3_;
        m0w = (unsigned)__shfl((int)w3sel, (lane - 16) & 63, 64);
      }
      if (s == 7) {
        m9w = (unsigned)__shfl((int)w0_, (lane + 16) & 63, 64);
      } else {
        const unsigned w0sel = (quad == 0) ? rb[dy][s + 1][0] : w0_;
        m9w = (unsigned)__shfl((int)w0sel, (lane + 16) & 63, 64);
      }
      m[0] = (s == 0 && quad == 0) ? 0.f : hif(m0w);
      m[9] = (s == 7 && quad == 3) ? 0.f : lof(m9w);
      const float W0 = wreg[dy * 3], W1 = wreg[dy * 3 + 1], W2 = wreg[dy * 3 + 2];
#pragma unroll
      for (int j = 0; j < 8; ++j)
        a[j] = fmaf(W2, m[j + 2], fmaf(W1, m[j + 1], fmaf(W0, m[j], a[j])));
    }
    short8 frag;
#pragma unroll
    for (int j = 0; j < 8; ++j) frag[j] = f2bf(a[j]);
    acc = __builtin_amdgcn_mfma_f32_16x16x32_bf16(frag, frag, acc, 0, 0, 0);
  }
#pragma unroll
  for (int reg = 0; reg < 4; ++reg)
    red[wave][(quad * 4 + reg) * 16 + l15] = acc[reg];
  __syncthreads();
  {
    const int e = threadIdx.x;
    const float s4 = red[0][e] + red[1][e] + red[2][e] + red[3][e];
    atomicAdd(&gram2[bh * 256 + e], s4);
  }
}

// ---------------------------------------------------------------------------
// K3 (+prep2 tail): m1 1x1 conv + BN -> y_t[b,n,64] bf16. LDS stride 66.
// Tail blocks (>=4096) pack w2 -> apw2 (after k_gram, before k_conv5).
__global__ __launch_bounds__(256, 4) void k_m1_bn(const short* __restrict__ x_t,
    const short* __restrict__ apm, const float* __restrict__ gamma,
    const float* __restrict__ beta, const float* __restrict__ mean,
    const float* __restrict__ var, short* __restrict__ y_t,
    const float* __restrict__ w2, short* __restrict__ apw2) {
  if (blockIdx.x >= 4096) {  // folded k_prep2
    const int bid = blockIdx.x - 4096;
    for (int idx = bid * 256 + threadIdx.x; idx < 25 * 2 * 4 * 64 * 8; idx += 16384) {
      const int j = idx & 7, lane = (idx >> 3) & 63, mt = (idx >> 9) & 3,
                cc = (idx >> 11) & 1, t = idx >> 12;
      const int o = mt * 16 + (lane & 15);
      const int c = cc * 32 + (lane >> 4) * 8 + j;
      apw2[idx] = f2bf(w2[((size_t)o * 64 + c) * 25 + t]);
    }
    return;
  }
  __shared__ short lds[64 * 66];
  const int b = blockIdx.x >> 10, ntile = blockIdx.x & 1023;
  const int wave = threadIdx.x >> 6, lane = threadIdx.x & 63;
  const int quad = lane >> 4, l15 = lane & 15;
  const int n = ntile * 64 + wave * 16 + l15;
  f32x4 acc[4];
#pragma unroll
  for (int mt = 0; mt < 4; ++mt) acc[mt] = (f32x4){0.f, 0.f, 0.f, 0.f};
#pragma unroll
  for (int cc = 0; cc < 2; ++cc) {
    const short8 bf = *(const short8*)(x_t + ((size_t)(b * NN + n)) * 64 + cc * 32 + quad * 8);
#pragma unroll
    for (int mt = 0; mt < 4; ++mt) {
      const short8 af = *(const short8*)(apm + ((cc * 4 + mt) * 64 + lane) * 8);
      acc[mt] = __builtin_amdgcn_mfma_f32_16x16x32_bf16(af, bf, acc[mt], 0, 0, 0);
    }
  }
#pragma unroll
  for (int mt = 0; mt < 4; ++mt)
#pragma unroll
    for (int reg = 0; reg < 4; ++reg) {
      const int o = mt * 16 + quad * 4 + reg;
      const float sc = gamma[o] * rsqrtf(var[o] + 1e-5f);
      lds[(wave * 16 + l15) * 66 + o] = f2bf((acc[mt][reg] - mean[o]) * sc + beta[o]);
    }
  __syncthreads();
  short* dst = y_t + ((size_t)(b * NN + ntile * 64)) * 64;
#pragma unroll
  for (int it = 0; it < 2; ++it) {
    const int idx = it * 256 + threadIdx.x;
    const int lcol = idx >> 3, cb = idx & 7;
    *(short8*)(dst + (size_t)lcol * 64 + cb * 8) = *(const short8*)(lds + lcol * 66 + cb * 8);
  }
}

// ---------------------------------------------------------------------------
// K4: conv5x5 implicit-GEMM MFMA — REVERTED to the round-6 best (64.4 us):
// 8-ROW TILE (512 blocks = 2/CU), two cc phases, XOR-swizzled staging
// (conflict-free), (256,2) -> no spill. R7's single-phase variant regressed
// (73.9) by doubling apw2 L2 traffic and per-output staging.
// Staging: L = rr*68+col (rr<12), cb 16B; byte = (L*64+cb*16) ^ (((L>>1)&3)<<4).
__global__ __launch_bounds__(256, 2) void k_conv5(const short* __restrict__ y_t,
    const short* __restrict__ apw2, const short* __restrict__ x_t,
    short* __restrict__ v_t) {
  __shared__ short slds[8 * 64 * 76];  // 77,824 B >= staging 12*68*64B = 52,224 B
  char* sb = (char*)slds;
  const int b = blockIdx.x >> 7;
  const int rg = (blockIdx.x >> 2) & 31, cg = blockIdx.x & 3;
  const int r0 = rg * 8, x0 = cg * 64;
  const int wave = threadIdx.x >> 6, lane = threadIdx.x & 63;
  const int quad = lane >> 4, l15 = lane & 15;
  f32x4 acc[4][2][4];
#pragma unroll
  for (int mt = 0; mt < 4; ++mt)
#pragma unroll
    for (int r = 0; r < 2; ++r)
#pragma unroll
      for (int nt = 0; nt < 4; ++nt) acc[mt][r][nt] = (f32x4){0.f, 0.f, 0.f, 0.f};
  for (int cc = 0; cc < 2; ++cc) {
    if (cc) __syncthreads();
    for (int idx = threadIdx.x; idx < 12 * 68 * 4; idx += 256) {
      const int rr = idx / 272, rem = idx - rr * 272;
      const int col = rem >> 2, cb = rem & 3;
      const int gr = r0 - 2 + rr, gc = x0 - 2 + col;
      short8 val = {0, 0, 0, 0, 0, 0, 0, 0};
      if (gr >= 0 && gr < 256 && gc >= 0 && gc < 256)
        val = *(const short8*)(y_t + ((size_t)(b * NN + gr * 256 + gc)) * 64 + cc * 32 + cb * 8);
      const int L = rr * 68 + col;
      *(short8*)(sb + ((L * 64 + cb * 16) ^ (((L >> 1) & 3) << 4))) = val;
    }
    __syncthreads();
    for (int t = 0; t < 25; ++t) {
      const int dy = t / 5 - 2, dx = t % 5 - 2;
      short8 a[4];
#pragma unroll
      for (int mt = 0; mt < 4; ++mt)
        a[mt] = *(const short8*)(apw2 + (((t * 2 + cc) * 4 + mt) * 64 + lane) * 8);
#pragma unroll
      for (int r = 0; r < 2; ++r) {
        const int rr = wave * 2 + r + 2 + dy;
#pragma unroll
        for (int nt = 0; nt < 4; ++nt) {
          const int L = rr * 68 + nt * 16 + l15 + 2 + dx;
          const short8 bf =
              *(const short8*)(sb + ((L * 64 + quad * 16) ^ (((L >> 1) & 3) << 4)));
#pragma unroll
          for (int mt = 0; mt < 4; ++mt)
            acc[mt][r][nt] =
                __builtin_amdgcn_mfma_f32_16x16x32_bf16(a[mt], bf, acc[mt][r][nt], 0, 0, 0);
        }
      }
    }
  }
  __syncthreads();  // done reading staging; reuse slds as [row8][col64] stride 76
#pragma unroll
  for (int r = 0; r < 2; ++r) {
    const int lrow = wave * 2 + r;
    const int row = r0 + lrow;
#pragma unroll
    for (int nt = 0; nt < 4; ++nt) {
      const int lcol = nt * 16 + l15;
      const short* xp = x_t + ((size_t)(b * NN + row * 256 + x0 + lcol)) * 64 + quad * 4;
#pragma unroll
      for (int mt = 0; mt < 4; ++mt) {
        const short4b xv4 = *(const short4b*)(xp + mt * 16);
        short4b pk;
#pragma unroll
        for (int reg = 0; reg < 4; ++reg) {
          const float sg = 1.f / (1.f + __expf(-acc[mt][r][nt][reg]));
          pk[reg] = f2bf(bf2f(xv4[reg]) * (1.f + sg));
        }
        *(short4b*)(slds + (lrow * 64 + lcol) * 76 + mt * 16 + quad * 4) = pk;
      }
    }
  }
  __syncthreads();
#pragma unroll
  for (int it = 0; it < 16; ++it) {
    const int idx = it * 256 + threadIdx.x;
    const int cb = idx & 7, lcol = (idx >> 3) & 63, rr = idx >> 9;
    *(short8*)(v_t + ((size_t)(b * NN + (r0 + rr) * 256 + x0 + lcol)) * 64 + cb * 8) =
        *(const short8*)(slds + (rr * 64 + lcol) * 76 + cb * 8);
  }
}

// ---------------------------------------------------------------------------
// K5: softmax from gram2, fold wproj, emit E in bf16 A-frag order. Grid 16.
__global__ __launch_bounds__(256) void k_attn_e(const float* __restrict__ gram2,
    const float* __restrict__ temp, const float* __restrict__ wproj,
    short* __restrict__ Epack) {
  __shared__ float attn[2048];
  const int t = threadIdx.x;
  {
    const int b = t >> 6, h = (t >> 3) & 7, c = t & 7;
    const float* g = gram2 + (b * 8 + h) * 256;
    const float qn = fmaxf(sqrtf(g[c * 16 + c]), 1e-12f);
    const float tp = temp[h];
    float row[8];
    float mx = -1e30f;
#pragma unroll
    for (int d = 0; d < 8; ++d) {
      const float kn = fmaxf(sqrtf(g[(8 + d) * 16 + (8 + d)]), 1e-12f);
      row[d] = g[c * 16 + 8 + d] / (qn * kn) * tp;
      mx = fmaxf(mx, row[d]);
    }
    float s = 0.f;
#pragma unroll
    for (int d = 0; d < 8; ++d) { row[d] = __expf(row[d] - mx); s += row[d]; }
    const float inv = 1.f / s;
#pragma unroll
    for (int d = 0; d < 8; ++d) attn[t * 8 + d] = row[d] * inv;
  }
  __syncthreads();
  for (int idx = blockIdx.x * 1024 + t; idx < (blockIdx.x + 1) * 1024; idx += 256) {
    const int j = idx & 7, lane = (idx >> 3) & 63, mt = (idx >> 9) & 3,
              cc = (idx >> 11) & 1, b = idx >> 12;
    const int o = mt * 16 + (lane & 15);
    const int cv = cc * 32 + (lane >> 4) * 8 + j;
    const int h = cv >> 3, d = cv & 7;
    float a = 0.f;
#pragma unroll
    for (int c2 = 0; c2 < 8; ++c2)
      a += wproj[o * 64 + h * 8 + c2] * attn[((b * 8 + h) * 8 + c2) * 8 + d];
    Epack[idx] = f2bf(a);
  }
}

// ---------------------------------------------------------------------------
// K6: out[b,o,n] = bproj[o] + E[b].v_t  as per-batch MFMA GEMM, fp32 stores.
__global__ __launch_bounds__(256, 4) void k_out(const short* __restrict__ v_t,
    const short* __restrict__ Epack, const float* __restrict__ bproj,
    float* __restrict__ out) {
  const int b = blockIdx.x >> 10, ntile = blockIdx.x & 1023;
  const int wave = threadIdx.x >> 6, lane = threadIdx.x & 63;
  const int quad = lane >> 4, l15 = lane & 15;
  const int n = ntile * 64 + wave * 16 + l15;
  f32x4 acc[4];
#pragma unroll
  for (int mt = 0; mt < 4; ++mt) acc[mt] = (f32x4){0.f, 0.f, 0.f, 0.f};
#pragma unroll
  for (int cc = 0; cc < 2; ++cc) {
    const short8 bf = *(const short8*)(v_t + ((size_t)(b * NN + n)) * 64 + cc * 32 + quad * 8);
#pragma unroll
    for (int mt = 0; mt < 4; ++mt) {
      const short8 af = *(const short8*)(Epack + (((b * 2 + cc) * 4 + mt) * 64 + lane) * 8);
      acc[mt] = __builtin_amdgcn_mfma_f32_16x16x32_bf16(af, bf, acc[mt], 0, 0, 0);
    }
  }
#pragma unroll
  for (int mt = 0; mt < 4; ++mt)
#pragma unroll
    for (int reg = 0; reg < 4; ++reg) {
      const int o = mt * 16 + quad * 4 + reg;
      out[((size_t)(b * 64 + o)) * NN + n] = acc[mt][reg] + bproj[o];
    }
}

// ---------------------------------------------------------------------------
// Workspace (byte offsets), total 134307840 <= proven ws capacity:
//  [0,   64M)  qk bf16 [b][128][N]  -> after k_gram: v_t [0,32M), apw2 @32M
//  [64M, 96M)  x_t bf16 [b][n][64]
//  [96M,128M)  y_t bf16 [b][n][64]
//  [128M, ..)  gram2 32KB | apk 16KB | apm 8KB | Epack 32KB
extern "C" void kernel_launch(void* const* d_in, const int* in_sizes, int n_in,
                              void* d_out, int out_size, void* d_ws, size_t ws_size,
                              hipStream_t stream) {
  const float* x     = (const float*)d_in[0];
  const float* wqkv  = (const float*)d_in[1];
  const float* bqkv  = (const float*)d_in[2];
  const float* wdw   = (const float*)d_in[3];
  const float* bdw   = (const float*)d_in[4];
  const float* wproj = (const float*)d_in[5];
  const float* bproj = (const float*)d_in[6];
  const float* temp  = (const float*)d_in[7];
  const float* wm1   = (const float*)d_in[8];
  const float* gamma = (const float*)d_in[9];
  const float* beta  = (const float*)d_in[10];
  const float* mean  = (const float*)d_in[11];
  const float* var   = (const float*)d_in[12];
  const float* wm2   = (const float*)d_in[13];

  char* wsb = (char*)d_ws;
  short* qk    = (short*)(wsb);
  short* v_t   = (short*)(wsb);                       // aliases qk (after k_gram)
  short* apw2  = (short*)(wsb + 33554432);            // aliases qk tail (after k_gram)
  short* x_t   = (short*)(wsb + 67108864);
  short* y_t   = (short*)(wsb + 100663296);
  float* gram2 = (float*)(wsb + 134217728);
  short* apk   = (short*)(wsb + 134217728 + 32768);
  short* apm   = (short*)(wsb + 134217728 + 49152);
  short* Epack = (short*)(wsb + 134217728 + 57344);
  float* out   = (float*)d_out;

  k_xt<<<dim3(1088), dim3(256), 0, stream>>>(x, x_t, wqkv, wm1, apk, apm, gram2);
  k_qk1x1<<<dim3(4096), dim3(256), 0, stream>>>(x_t, apk, bqkv, qk);
  k_gram<<<dim3(2048), dim3(256), 0, stream>>>(qk, wdw, bdw, gram2);
  k_m1_bn<<<dim3(4160), dim3(256), 0, stream>>>(x_t, apm, gamma, beta, mean, var, y_t,
                                                wm2, apw2);
  k_conv5<<<dim3(512), dim3(256), 0, stream>>>(y_t, apw2, x_t, v_t);
  k_attn_e<<<dim3(16), dim3(256), 0, stream>>>(gram2, temp, wproj, Epack);
  k_out<<<dim3(4096), dim3(256), 0, stream>>>(v_t, Epack, bproj, out);
}

// Round 9
// 288.324 us; speedup vs baseline: 1.3719x; 1.0179x over previous
//
#include <hip/hip_runtime.h>
#include <math.h>

#define B 4
#define C 64
#define NN 65536

typedef __attribute__((ext_vector_type(8))) short short8;
typedef __attribute__((ext_vector_type(4))) short short4b;
typedef __attribute__((ext_vector_type(4))) float f32x4;
typedef __attribute__((ext_vector_type(4))) unsigned int u32x4;

__device__ inline float bf2f(short s) {
  union { unsigned u; float f; } v; v.u = ((unsigned)(unsigned short)s) << 16; return v.f;
}
__device__ inline short f2bf(float f) {
  union { float f; unsigned u; } v; v.f = f;
  unsigned r = v.u + 0x7FFFu + ((v.u >> 16) & 1u);  // RNE
  return (short)(r >> 16);
}
// bf16 pair unpack: low half / high half of a 32-bit word.
__device__ inline float lof(unsigned u) {
  union { unsigned u; float f; } v; v.u = u << 16; return v.f;
}
__device__ inline float hif(unsigned u) {
  union { unsigned u; float f; } v; v.u = u & 0xffff0000u; return v.f;
}

// ---------------------------------------------------------------------------
// P1: pack w_qkv (first 128 rows) and w_m1 into MFMA A-frag order; zero gram2.
// Standalone (its outputs are consumed by k_fused, so it can't ride there).
__global__ void k_prep1(const float* __restrict__ wqkv, const float* __restrict__ wm1,
    short* __restrict__ apk, short* __restrict__ apm, float* __restrict__ gram2) {
  for (int idx = blockIdx.x * 256 + threadIdx.x; idx < 20480; idx += 16384) {
    if (idx < 8192) {
      const int j = idx & 7, lane = (idx >> 3) & 63, mt = (idx >> 9) & 7, cc = idx >> 12;
      const int o = mt * 16 + (lane & 15), c = cc * 32 + (lane >> 4) * 8 + j;
      apk[idx] = f2bf(wqkv[o * 64 + c]);
    } else if (idx < 12288) {
      const int k = idx - 8192;
      const int j = k & 7, lane = (k >> 3) & 63, mt = (k >> 9) & 3, cc = k >> 11;
      const int o = mt * 16 + (lane & 15), c = cc * 32 + (lane >> 4) * 8 + j;
      apm[k] = f2bf(wm1[o * 64 + c]);
    } else {
      gram2[idx - 12288] = 0.f;
    }
  }
}

// ---------------------------------------------------------------------------
// FUSED xt + qk1x1 + m1_bn: per block, transpose a 64-px x-slab into LDS
// (stride 66: b16 write bank = nl%32, 2-way = free), then run BOTH 1x1-conv
// GEMMs with B-frags read straight from LDS (values bit-identical to the old
// x_t global reads), emitting x_t, qk, and y_t. Kills 64 MB of x_t re-reads
// and two kernel-launch drains.
__global__ __launch_bounds__(256, 4) void k_fused(const float* __restrict__ x,
    const short* __restrict__ apk, const float* __restrict__ bqkv,
    const short* __restrict__ apm, const float* __restrict__ gamma,
    const float* __restrict__ beta, const float* __restrict__ mean,
    const float* __restrict__ var, short* __restrict__ x_t,
    short* __restrict__ qk, short* __restrict__ y_t) {
  __shared__ short lds[64 * 66];
  const int b = blockIdx.x >> 10, ntile = blockIdx.x & 1023;
  const int n0 = ntile * 64;
  const int t = threadIdx.x;
  const int wave = t >> 6, lane = t & 63;
  const int quad = lane >> 4, l15 = lane & 15;
  // Load + transpose x (fp32; 64 consecutive floats per c = 256B coalesced).
#pragma unroll
  for (int it = 0; it < 16; ++it) {
    const int idx = it * 256 + t;
    const int c = idx >> 6, nl = idx & 63;
    lds[nl * 66 + c] = f2bf(x[((size_t)(b * 64 + c)) * NN + n0 + nl]);
  }
  __syncthreads();
  // x_t write (channel-innermost), straight from the transpose buffer.
  {
    short* dst = x_t + ((size_t)(b * NN + n0)) * 64;
#pragma unroll
    for (int it = 0; it < 2; ++it) {
      const int idx = it * 256 + t;
      const int nl = idx >> 3, cb = idx & 7;
      *(short8*)(dst + (size_t)nl * 64 + cb * 8) = *(const short8*)(lds + nl * 66 + cb * 8);
    }
  }
  const int nloc = wave * 16 + l15;
  const int n = n0 + nloc;
  // qk GEMM (128 outputs).
  {
    f32x4 acc[8];
#pragma unroll
    for (int mt = 0; mt < 8; ++mt) acc[mt] = (f32x4){0.f, 0.f, 0.f, 0.f};
#pragma unroll
    for (int cc = 0; cc < 2; ++cc) {
      const short8 bf = *(const short8*)(lds + nloc * 66 + cc * 32 + quad * 8);
#pragma unroll
      for (int mt = 0; mt < 8; ++mt) {
        const short8 af = *(const short8*)(apk + ((cc * 8 + mt) * 64 + lane) * 8);
        acc[mt] = __builtin_amdgcn_mfma_f32_16x16x32_bf16(af, bf, acc[mt], 0, 0, 0);
      }
    }
#pragma unroll
    for (int mt = 0; mt < 8; ++mt)
#pragma unroll
      for (int reg = 0; reg < 4; ++reg) {
        const int o = mt * 16 + quad * 4 + reg;
        qk[((size_t)(b * 128 + o)) * NN + n] = f2bf(acc[mt][reg] + bqkv[o]);
      }
  }
  // m1 GEMM + BN (64 outputs).
  f32x4 acc2[4];
#pragma unroll
  for (int mt = 0; mt < 4; ++mt) acc2[mt] = (f32x4){0.f, 0.f, 0.f, 0.f};
#pragma unroll
  for (int cc = 0; cc < 2; ++cc) {
    const short8 bf = *(const short8*)(lds + nloc * 66 + cc * 32 + quad * 8);
#pragma unroll
    for (int mt = 0; mt < 4; ++mt) {
      const short8 af = *(const short8*)(apm + ((cc * 4 + mt) * 64 + lane) * 8);
      acc2[mt] = __builtin_amdgcn_mfma_f32_16x16x32_bf16(af, bf, acc2[mt], 0, 0, 0);
    }
  }
  __syncthreads();  // all transpose-buffer reads done; safe to overwrite
#pragma unroll
  for (int mt = 0; mt < 4; ++mt)
#pragma unroll
    for (int reg = 0; reg < 4; ++reg) {
      const int o = mt * 16 + quad * 4 + reg;
      const float sc = gamma[o] * rsqrtf(var[o] + 1e-5f);
      lds[nloc * 66 + o] = f2bf((acc2[mt][reg] - mean[o]) * sc + beta[o]);
    }
  __syncthreads();
  {
    short* dst = y_t + ((size_t)(b * NN + n0)) * 64;
#pragma unroll
    for (int it = 0; it < 2; ++it) {
      const int idx = it * 256 + t;
      const int nl = idx >> 3, cb = idx & 7;
      *(short8*)(dst + (size_t)nl * 64 + cb * 8) = *(const short8*)(lds + nl * 66 + cb * 8);
    }
  }
}

// ---------------------------------------------------------------------------
// K2: FUSED depthwise-3x3 + Gram, register-hoisted rows, single-shfl edges.
// Unchanged from round 8.
__global__ __launch_bounds__(256, 3) void k_gram(const short* __restrict__ qk,
    const float* __restrict__ wdw, const float* __restrict__ bdw,
    float* __restrict__ gram2) {
  __shared__ float red[4][256];
  const int bh = blockIdx.x >> 6, chunk = blockIdx.x & 63;
  const int b = bh >> 3, h = bh & 7;
  const int wave = threadIdx.x >> 6, lane = threadIdx.x & 63;
  const int quad = lane >> 4, l15 = lane & 15;
  const int ch = (l15 < 8) ? (h * 8 + l15) : (64 + h * 8 + (l15 - 8));
  const short* plane = qk + ((size_t)(b * 128 + ch)) * NN;
  float wreg[9];
#pragma unroll
  for (int i = 0; i < 9; ++i) wreg[i] = wdw[ch * 9 + i];
  const float bias = bdw[ch];
  const int row = chunk * 4 + wave;          // wave-uniform output row 0..255
  const short* prow = plane + row * 256;
  u32x4 rb[3][8];
#pragma unroll
  for (int dy = 0; dy < 3; ++dy) {
    if (dy == 0 && row == 0) continue;       // wave-uniform
    if (dy == 2 && row == 255) continue;
    const short* pr = prow + (dy - 1) * 256 + quad * 8;
#pragma unroll
    for (int s = 0; s < 8; ++s)
      rb[dy][s] = *(const u32x4*)(pr + s * 32);
  }
  f32x4 acc = {0.f, 0.f, 0.f, 0.f};
#pragma unroll
  for (int s = 0; s < 8; ++s) {
    float a[8];
#pragma unroll
    for (int j = 0; j < 8; ++j) a[j] = bias;
#pragma unroll
    for (int dy = 0; dy < 3; ++dy) {
      if (dy == 0 && row == 0) continue;     // wave-uniform (shfls stay full-wave)
      if (dy == 2 && row == 255) continue;
      const unsigned w0_ = rb[dy][s][0], w1_ = rb[dy][s][1],
                     w2_ = rb[dy][s][2], w3_ = rb[dy][s][3];
      float m[10];
      m[1] = lof(w0_); m[2] = hif(w0_);
      m[3] = lof(w1_); m[4] = hif(w1_);
      m[5] = lof(w2_); m[6] = hif(w2_);
      m[7] = lof(w3_); m[8] = hif(w3_);
      unsigned m0w, m9w;
      if (s == 0) {
        m0w = (unsigned)__shfl((int)w3_, (lane - 16) & 63, 64);
      } else {
        const unsigned w3sel = (quad == 3) ? rb[dy][s - 1][3] : w3_;
        m0w = (unsigned)__shfl((int)w3sel, (lane - 16) & 63, 64);
      }
      if (s == 7) {
        m9w = (unsigned)__shfl((int)w0_, (lane + 16) & 63, 64);
      } else {
        const unsigned w0sel = (quad == 0) ? rb[dy][s + 1][0] : w0_;
        m9w = (unsigned)__shfl((int)w0sel, (lane + 16) & 63, 64);
      }
      m[0] = (s == 0 && quad == 0) ? 0.f : hif(m0w);
      m[9] = (s == 7 && quad == 3) ? 0.f : lof(m9w);
      const float W0 = wreg[dy * 3], W1 = wreg[dy * 3 + 1], W2 = wreg[dy * 3 + 2];
#pragma unroll
      for (int j = 0; j < 8; ++j)
        a[j] = fmaf(W2, m[j + 2], fmaf(W1, m[j + 1], fmaf(W0, m[j], a[j])));
    }
    short8 frag;
#pragma unroll
    for (int j = 0; j < 8; ++j) frag[j] = f2bf(a[j]);
    acc = __builtin_amdgcn_mfma_f32_16x16x32_bf16(frag, frag, acc, 0, 0, 0);
  }
#pragma unroll
  for (int reg = 0; reg < 4; ++reg)
    red[wave][(quad * 4 + reg) * 16 + l15] = acc[reg];
  __syncthreads();
  {
    const int e = threadIdx.x;
    const float s4 = red[0][e] + red[1][e] + red[2][e] + red[3][e];
    atomicAdd(&gram2[bh * 256 + e], s4);
  }
}

// ---------------------------------------------------------------------------
// P2+E: blocks 0..63 pack w2 -> apw2 (apw2 aliases dead qk: must run AFTER
// k_gram, which this launch position guarantees); blocks 64..79 do the
// softmax + wproj fold -> Epack (needs gram2, also post-gram).
__global__ __launch_bounds__(256) void k_prep2e(const float* __restrict__ w2,
    short* __restrict__ apw2, const float* __restrict__ gram2,
    const float* __restrict__ temp, const float* __restrict__ wproj,
    short* __restrict__ Epack) {
  if (blockIdx.x < 64) {
    for (int idx = blockIdx.x * 256 + threadIdx.x; idx < 25 * 2 * 4 * 64 * 8; idx += 16384) {
      const int j = idx & 7, lane = (idx >> 3) & 63, mt = (idx >> 9) & 3,
                cc = (idx >> 11) & 1, t = idx >> 12;
      const int o = mt * 16 + (lane & 15);
      const int c = cc * 32 + (lane >> 4) * 8 + j;
      apw2[idx] = f2bf(w2[((size_t)o * 64 + c) * 25 + t]);
    }
    return;
  }
  const int bid = blockIdx.x - 64;  // 0..15
  __shared__ float attn[2048];
  const int t = threadIdx.x;
  {
    const int b = t >> 6, h = (t >> 3) & 7, c = t & 7;
    const float* g = gram2 + (b * 8 + h) * 256;
    const float qn = fmaxf(sqrtf(g[c * 16 + c]), 1e-12f);
    const float tp = temp[h];
    float row[8];
    float mx = -1e30f;
#pragma unroll
    for (int d = 0; d < 8; ++d) {
      const float kn = fmaxf(sqrtf(g[(8 + d) * 16 + (8 + d)]), 1e-12f);
      row[d] = g[c * 16 + 8 + d] / (qn * kn) * tp;
      mx = fmaxf(mx, row[d]);
    }
    float s = 0.f;
#pragma unroll
    for (int d = 0; d < 8; ++d) { row[d] = __expf(row[d] - mx); s += row[d]; }
    const float inv = 1.f / s;
#pragma unroll
    for (int d = 0; d < 8; ++d) attn[t * 8 + d] = row[d] * inv;
  }
  __syncthreads();
  for (int idx = bid * 1024 + t; idx < (bid + 1) * 1024; idx += 256) {
    const int j = idx & 7, lane = (idx >> 3) & 63, mt = (idx >> 9) & 3,
              cc = (idx >> 11) & 1, b = idx >> 12;
    const int o = mt * 16 + (lane & 15);
    const int cv = cc * 32 + (lane >> 4) * 8 + j;
    const int h = cv >> 3, d = cv & 7;
    float a = 0.f;
#pragma unroll
    for (int c2 = 0; c2 < 8; ++c2)
      a += wproj[o * 64 + h * 8 + c2] * attn[((b * 8 + h) * 8 + c2) * 8 + d];
    Epack[idx] = f2bf(a);
  }
}

// ---------------------------------------------------------------------------
// K4: conv5x5 implicit-GEMM MFMA — frozen at the round-6/8 best: 8-ROW TILE
// (512 blocks = 2/CU), two cc phases, XOR-swizzled staging (conflict-free),
// (256,2) -> no spill.
// Staging: L = rr*68+col (rr<12), cb 16B; byte = (L*64+cb*16) ^ (((L>>1)&3)<<4).
__global__ __launch_bounds__(256, 2) void k_conv5(const short* __restrict__ y_t,
    const short* __restrict__ apw2, const short* __restrict__ x_t,
    short* __restrict__ v_t) {
  __shared__ short slds[8 * 64 * 76];  // 77,824 B >= staging 12*68*64B = 52,224 B
  char* sb = (char*)slds;
  const int b = blockIdx.x >> 7;
  const int rg = (blockIdx.x >> 2) & 31, cg = blockIdx.x & 3;
  const int r0 = rg * 8, x0 = cg * 64;
  const int wave = threadIdx.x >> 6, lane = threadIdx.x & 63;
  const int quad = lane >> 4, l15 = lane & 15;
  f32x4 acc[4][2][4];
#pragma unroll
  for (int mt = 0; mt < 4; ++mt)
#pragma unroll
    for (int r = 0; r < 2; ++r)
#pragma unroll
      for (int nt = 0; nt < 4; ++nt) acc[mt][r][nt] = (f32x4){0.f, 0.f, 0.f, 0.f};
  for (int cc = 0; cc < 2; ++cc) {
    if (cc) __syncthreads();
    for (int idx = threadIdx.x; idx < 12 * 68 * 4; idx += 256) {
      const int rr = idx / 272, rem = idx - rr * 272;
      const int col = rem >> 2, cb = rem & 3;
      const int gr = r0 - 2 + rr, gc = x0 - 2 + col;
      short8 val = {0, 0, 0, 0, 0, 0, 0, 0};
      if (gr >= 0 && gr < 256 && gc >= 0 && gc < 256)
        val = *(const short8*)(y_t + ((size_t)(b * NN + gr * 256 + gc)) * 64 + cc * 32 + cb * 8);
      const int L = rr * 68 + col;
      *(short8*)(sb + ((L * 64 + cb * 16) ^ (((L >> 1) & 3) << 4))) = val;
    }
    __syncthreads();
    for (int t = 0; t < 25; ++t) {
      const int dy = t / 5 - 2, dx = t % 5 - 2;
      short8 a[4];
#pragma unroll
      for (int mt = 0; mt < 4; ++mt)
        a[mt] = *(const short8*)(apw2 + (((t * 2 + cc) * 4 + mt) * 64 + lane) * 8);
#pragma unroll
      for (int r = 0; r < 2; ++r) {
        const int rr = wave * 2 + r + 2 + dy;
#pragma unroll
        for (int nt = 0; nt < 4; ++nt) {
          const int L = rr * 68 + nt * 16 + l15 + 2 + dx;
          const short8 bf =
              *(const short8*)(sb + ((L * 64 + quad * 16) ^ (((L >> 1) & 3) << 4)));
#pragma unroll
          for (int mt = 0; mt < 4; ++mt)
            acc[mt][r][nt] =
                __builtin_amdgcn_mfma_f32_16x16x32_bf16(a[mt], bf, acc[mt][r][nt], 0, 0, 0);
        }
      }
    }
  }
  __syncthreads();  // done reading staging; reuse slds as [row8][col64] stride 76
#pragma unroll
  for (int r = 0; r < 2; ++r) {
    const int lrow = wave * 2 + r;
    const int row = r0 + lrow;
#pragma unroll
    for (int nt = 0; nt < 4; ++nt) {
      const int lcol = nt * 16 + l15;
      const short* xp = x_t + ((size_t)(b * NN + row * 256 + x0 + lcol)) * 64 + quad * 4;
#pragma unroll
      for (int mt = 0; mt < 4; ++mt) {
        const short4b xv4 = *(const short4b*)(xp + mt * 16);
        short4b pk;
#pragma unroll
        for (int reg = 0; reg < 4; ++reg) {
          const float sg = 1.f / (1.f + __expf(-acc[mt][r][nt][reg]));
          pk[reg] = f2bf(bf2f(xv4[reg]) * (1.f + sg));
        }
        *(short4b*)(slds + (lrow * 64 + lcol) * 76 + mt * 16 + quad * 4) = pk;
      }
    }
  }
  __syncthreads();
#pragma unroll
  for (int it = 0; it < 16; ++it) {
    const int idx = it * 256 + threadIdx.x;
    const int cb = idx & 7, lcol = (idx >> 3) & 63, rr = idx >> 9;
    *(short8*)(v_t + ((size_t)(b * NN + (r0 + rr) * 256 + x0 + lcol)) * 64 + cb * 8) =
        *(const short8*)(slds + (rr * 64 + lcol) * 76 + cb * 8);
  }
}

// ---------------------------------------------------------------------------
// K6: out[b,o,n] = bproj[o] + E[b].v_t  as per-batch MFMA GEMM, fp32 stores.
__global__ __launch_bounds__(256, 4) void k_out(const short* __restrict__ v_t,
    const short* __restrict__ Epack, const float* __restrict__ bproj,
    float* __restrict__ out) {
  const int b = blockIdx.x >> 10, ntile = blockIdx.x & 1023;
  const int wave = threadIdx.x >> 6, lane = threadIdx.x & 63;
  const int quad = lane >> 4, l15 = lane & 15;
  const int n = ntile * 64 + wave * 16 + l15;
  f32x4 acc[4];
#pragma unroll
  for (int mt = 0; mt < 4; ++mt) acc[mt] = (f32x4){0.f, 0.f, 0.f, 0.f};
#pragma unroll
  for (int cc = 0; cc < 2; ++cc) {
    const short8 bf = *(const short8*)(v_t + ((size_t)(b * NN + n)) * 64 + cc * 32 + quad * 8);
#pragma unroll
    for (int mt = 0; mt < 4; ++mt) {
      const short8 af = *(const short8*)(Epack + (((b * 2 + cc) * 4 + mt) * 64 + lane) * 8);
      acc[mt] = __builtin_amdgcn_mfma_f32_16x16x32_bf16(af, bf, acc[mt], 0, 0, 0);
    }
  }
#pragma unroll
  for (int mt = 0; mt < 4; ++mt)
#pragma unroll
    for (int reg = 0; reg < 4; ++reg) {
      const int o = mt * 16 + quad * 4 + reg;
      out[((size_t)(b * 64 + o)) * NN + n] = acc[mt][reg] + bproj[o];
    }
}

// ---------------------------------------------------------------------------
// Workspace (byte offsets), total 134307840 <= proven ws capacity:
//  [0,   64M)  qk bf16 [b][128][N]  -> after k_gram: v_t [0,32M), apw2 @32M
//  [64M, 96M)  x_t bf16 [b][n][64]
//  [96M,128M)  y_t bf16 [b][n][64]
//  [128M, ..)  gram2 32KB | apk 16KB | apm 8KB | Epack 32KB
extern "C" void kernel_launch(void* const* d_in, const int* in_sizes, int n_in,
                              void* d_out, int out_size, void* d_ws, size_t ws_size,
                              hipStream_t stream) {
  const float* x     = (const float*)d_in[0];
  const float* wqkv  = (const float*)d_in[1];
  const float* bqkv  = (const float*)d_in[2];
  const float* wdw   = (const float*)d_in[3];
  const float* bdw   = (const float*)d_in[4];
  const float* wproj = (const float*)d_in[5];
  const float* bproj = (const float*)d_in[6];
  const float* temp  = (const float*)d_in[7];
  const float* wm1   = (const float*)d_in[8];
  const float* gamma = (const float*)d_in[9];
  const float* beta  = (const float*)d_in[10];
  const float* mean  = (const float*)d_in[11];
  const float* var   = (const float*)d_in[12];
  const float* wm2   = (const float*)d_in[13];

  char* wsb = (char*)d_ws;
  short* qk    = (short*)(wsb);
  short* v_t   = (short*)(wsb);                       // aliases qk (after k_gram)
  short* apw2  = (short*)(wsb + 33554432);            // aliases qk tail (after k_gram)
  short* x_t   = (short*)(wsb + 67108864);
  short* y_t   = (short*)(wsb + 100663296);
  float* gram2 = (float*)(wsb + 134217728);
  short* apk   = (short*)(wsb + 134217728 + 32768);
  short* apm   = (short*)(wsb + 134217728 + 49152);
  short* Epack = (short*)(wsb + 134217728 + 57344);
  float* out   = (float*)d_out;

  k_prep1<<<dim3(64), dim3(256), 0, stream>>>(wqkv, wm1, apk, apm, gram2);
  k_fused<<<dim3(4096), dim3(256), 0, stream>>>(x, apk, bqkv, apm, gamma, beta,
                                                mean, var, x_t, qk, y_t);
  k_gram<<<dim3(2048), dim3(256), 0, stream>>>(qk, wdw, bdw, gram2);
  k_prep2e<<<dim3(80), dim3(256), 0, stream>>>(wm2, apw2, gram2, temp, wproj, Epack);
  k_conv5<<<dim3(512), dim3(256), 0, stream>>>(y_t, apw2, x_t, v_t);
  k_out<<<dim3(4096), dim3(256), 0, stream>>>(v_t, Epack, bproj, out);
}